// Round 5
// baseline (191.068 us; speedup 1.0000x reference)
//
#include <hip/hip_runtime.h>
#include <math.h>

#define S_DIM 8
#define N_RES 256
#define MSA_DIM 256
#define PAIR_DIM 128
#define D_DIM 32
#define H_DIM 8
#define M_ROWS (S_DIM * N_RES)      // 2048
#define QKV_N (3 * H_DIM * D_DIM)   // 768
#define HD (H_DIM * D_DIM)          // 256
#define LOG2E 1.4426950408889634f

// ---- wave64 sum via DPP; total lands in lane 63
#define DPP_ADD(x, ctrl, rmask)                                                \
    x += __int_as_float(__builtin_amdgcn_update_dpp(                           \
        0, __float_as_int(x), (ctrl), (rmask), 0xf, true))

__device__ __forceinline__ float wave_sum63(float x) {
    DPP_ADD(x, 0x111, 0xf);   // row_shr:1
    DPP_ADD(x, 0x112, 0xf);   // row_shr:2
    DPP_ADD(x, 0x114, 0xf);   // row_shr:4
    DPP_ADD(x, 0x118, 0xf);   // row_shr:8
    DPP_ADD(x, 0x142, 0xa);   // row_bcast:15 -> rows 1,3
    DPP_ADD(x, 0x143, 0xc);   // row_bcast:31 -> rows 2,3
    return x;
}

// sum over the 4 lanes of a quad (all quad lanes end with the total)
__device__ __forceinline__ float quad_sum(float x) {
    x += __int_as_float(__builtin_amdgcn_update_dpp(
        0, __float_as_int(x), 0xB1, 0xf, 0xf, true));  // quad_perm [1,0,3,2]
    x += __int_as_float(__builtin_amdgcn_update_dpp(
        0, __float_as_int(x), 0x4E, 0xf, 0xf, true));  // quad_perm [2,3,0,1]
    return x;
}

// ---------------- Kernel 1: LayerNorm of msa rows -> x [2048,256] ----------
__global__ __launch_bounds__(256) void ln_msa_kernel(
    const float* __restrict__ msa, const float* __restrict__ w,
    const float* __restrict__ b, float* __restrict__ x)
{
    int row = blockIdx.x;
    int t = threadIdx.x;
    float v = msa[row * MSA_DIM + t];
    float s1 = wave_sum63(v);
    float s2 = wave_sum63(v * v);
    __shared__ float r1[4], r2[4];
    int wave = t >> 6, lane = t & 63;
    if (lane == 63) { r1[wave] = s1; r2[wave] = s2; }
    __syncthreads();
    float S1 = r1[0] + r1[1] + r1[2] + r1[3];
    float S2 = r2[0] + r2[1] + r2[2] + r2[3];
    float mu = S1 * (1.0f / 256.0f);
    float var = S2 * (1.0f / 256.0f) - mu * mu;
    float rs = rsqrtf(var + 1e-5f);
    x[row * MSA_DIM + t] = (v - mu) * rs * w[t] + b[t];
}

// ------- Kernel 2: fused qkv+g GEMM, LDS only for X; W streamed from L1/L2 -
// tile 64m x 128n, thread = 4m x 8n; grid (8 n-tiles, 32 m-tiles) = 256 blocks
// bx<6 -> qkv cols (scatter to q/k/v [h][m][d]); bx>=6 -> gate (sigmoid)
__global__ __launch_bounds__(256) void xw_kernel(
    const float* __restrict__ X, const float* __restrict__ Wqkv,
    const float* __restrict__ Wg, float* __restrict__ q_t,
    float* __restrict__ k_t, float* __restrict__ v_t, float* __restrict__ g_t)
{
    __shared__ float Xs[16][68];
    int t = threadIdx.x;
    int bx = blockIdx.x;
    int qkv_mode = (bx < 6);
    int n0 = bx * 128;
    const float* W = qkv_mode ? Wqkv : Wg;
    int Ncols = qkv_mode ? QKV_N : HD;
    int wn0 = qkv_mode ? n0 : n0 - QKV_N;
    int m0 = blockIdx.y * 64;
    int tm = t >> 4, tn = t & 15;
    int lxm = t >> 2, lxk = (t & 3) * 4;
    const float* Wcol = W + wn0 + tn * 8;
    float acc[4][8] = {};
    float4 xa = *(const float4*)&X[(m0 + lxm) * 256 + lxk];
    for (int kt = 0; kt < 16; kt++) {
        __syncthreads();
        Xs[lxk + 0][lxm] = xa.x; Xs[lxk + 1][lxm] = xa.y;
        Xs[lxk + 2][lxm] = xa.z; Xs[lxk + 3][lxm] = xa.w;
        __syncthreads();
        if (kt < 15)
            xa = *(const float4*)&X[(m0 + lxm) * 256 + (kt + 1) * 16 + lxk];
#pragma unroll
        for (int kk = 0; kk < 16; kk++) {
            float a[4];
            *(float4*)a = *(const float4*)&Xs[kk][tm * 4];
            const float* wr = Wcol + (size_t)(kt * 16 + kk) * Ncols;
            float b[8];
            *(float4*)&b[0] = *(const float4*)&wr[0];
            *(float4*)&b[4] = *(const float4*)&wr[4];
#pragma unroll
            for (int i = 0; i < 4; i++)
#pragma unroll
                for (int u = 0; u < 8; u++) acc[i][u] += a[i] * b[u];
        }
    }
    int nbase = n0 + tn * 8;
#pragma unroll
    for (int i = 0; i < 4; i++) {
        int mm = m0 + tm * 4 + i;
#pragma unroll
        for (int u = 0; u < 8; u++) {
            float c = acc[i][u];
            int nn = nbase + u;
            if (qkv_mode) {
                int chunk = nn >> 8, r = nn & 255, d = r >> 3, h = r & 7;
                float* dst = (chunk == 0) ? q_t : ((chunk == 1) ? k_t : v_t);
                dst[(h * M_ROWS + mm) * D_DIM + d] = c;
            } else {
                int gn = nn - QKV_N;
                int d = gn >> 3, h = gn & 7;
                g_t[(h * M_ROWS + mm) * D_DIM + d] = 1.0f / (1.0f + __expf(-c));
            }
        }
    }
}

// ------- Kernel 2b: out GEMM, K-split 4 -> f32 partials in ws --------------
// ao layout [m][h*32+d]; w_out row for col k is (k&31)*8+(k>>5)
__global__ __launch_bounds__(256) void out_gemm_kernel(
    const float* __restrict__ X, const float* __restrict__ W,
    float* __restrict__ part)
{
    __shared__ float Xs[16][68];
    int t = threadIdx.x;
    int n0 = blockIdx.x * 128;
    int m0 = blockIdx.y * 64;
    int k0g = blockIdx.z * 64;
    int tm = t >> 4, tn = t & 15;
    int lxm = t >> 2, lxk = (t & 3) * 4;
    const float* Wcol = W + n0 + tn * 8;
    float acc[4][8] = {};
    float4 xa = *(const float4*)&X[(m0 + lxm) * 256 + k0g + lxk];
    for (int kt = 0; kt < 4; kt++) {
        __syncthreads();
        Xs[lxk + 0][lxm] = xa.x; Xs[lxk + 1][lxm] = xa.y;
        Xs[lxk + 2][lxm] = xa.z; Xs[lxk + 3][lxm] = xa.w;
        __syncthreads();
        if (kt < 3)
            xa = *(const float4*)&X[(m0 + lxm) * 256 + k0g + (kt + 1) * 16 + lxk];
#pragma unroll
        for (int kk = 0; kk < 16; kk++) {
            int k = k0g + kt * 16 + kk;
            int wrow = (k & 31) * 8 + (k >> 5);   // ao-layout -> w_out row
            float a[4];
            *(float4*)a = *(const float4*)&Xs[kk][tm * 4];
            const float* wr = Wcol + (size_t)wrow * 256;
            float b[8];
            *(float4*)&b[0] = *(const float4*)&wr[0];
            *(float4*)&b[4] = *(const float4*)&wr[4];
#pragma unroll
            for (int i = 0; i < 4; i++)
#pragma unroll
                for (int u = 0; u < 8; u++) acc[i][u] += a[i] * b[u];
        }
    }
    float* pb = part + (size_t)blockIdx.z * (M_ROWS * 256);
#pragma unroll
    for (int i = 0; i < 4; i++) {
        int mm = m0 + tm * 4 + i;
        *(float4*)&pb[mm * 256 + n0 + tn * 8] = *(float4*)&acc[i][0];
        *(float4*)&pb[mm * 256 + n0 + tn * 8 + 4] = *(float4*)&acc[i][4];
    }
}

// ------- Kernel 2c: reduce 4 partials + bias -> out ------------------------
__global__ __launch_bounds__(256) void reduce_out_kernel(
    const float* __restrict__ part, const float* __restrict__ bias,
    float* __restrict__ out)
{
    int idx = blockIdx.x * 256 + threadIdx.x;   // float4 index
    int e = idx * 4;
    int n = e & 255;
    float4 p0 = *(const float4*)&part[e];
    float4 p1 = *(const float4*)&part[e + M_ROWS * 256];
    float4 p2 = *(const float4*)&part[e + 2 * M_ROWS * 256];
    float4 p3 = *(const float4*)&part[e + 3 * M_ROWS * 256];
    float4 bb = *(const float4*)&bias[n];
    float4 o;
    o.x = p0.x + p1.x + p2.x + p3.x + bb.x;
    o.y = p0.y + p1.y + p2.y + p3.y + bb.y;
    o.z = p0.z + p1.z + p2.z + p3.z + bb.z;
    o.w = p0.w + p1.w + p2.w + p3.w + bb.w;
    *(float4*)&out[e] = o;
}

// ------- Kernel 3a: setup A'[c][h]=lw*wb*log2e [128][12], S'[8], C'[8] -----
__global__ __launch_bounds__(128) void pb_setup_kernel(
    const float* __restrict__ lw, const float* __restrict__ lb,
    const float* __restrict__ wb, float* __restrict__ Abuf)
{
    __shared__ float P[128][8], Q[128][8];
    int c = threadIdx.x;
    float lwc = lw[c], lbc = lb[c];
#pragma unroll
    for (int h = 0; h < 8; h++) {
        float w = wb[c * 8 + h];
        float a = lwc * w;
        P[c][h] = a;
        Q[c][h] = lbc * w;
        Abuf[c * 12 + h] = a * LOG2E;
    }
    __syncthreads();
    if (c < 8) {
        float s = 0, cc = 0;
        for (int k = 0; k < 128; k++) { s += P[k][c]; cc += Q[k][c]; }
        Abuf[1536 + c] = s * LOG2E;     // S'
        Abuf[1544 + c] = cc * LOG2E;    // C'
    }
}

// ------- Kernel 3b: pair bias b2[h][i][j] = log2e*(LN(pair[i,j,:]) @ w_b) --
__global__ __launch_bounds__(256) void pair_bias_kernel(
    const float* __restrict__ pair, const float* __restrict__ Abuf,
    float* __restrict__ b2)
{
    __shared__ __align__(16) float As[1552];   // [128][12] + S'[8] + C'[8]
    int t = threadIdx.x;
    for (int idx = t; idx < 388; idx += 256)
        ((float4*)As)[idx] = ((const float4*)Abuf)[idx];
    __syncthreads();
    int row = blockIdx.x * 64 + (t >> 2);
    int q = t & 3;
    const float* in = pair + (size_t)row * PAIR_DIM;
    float4 x4[8];
#pragma unroll
    for (int it = 0; it < 8; it++)
        x4[it] = *(const float4*)&in[it * 16 + q * 4];
    float s = 0, s2 = 0;
    float dot[8] = {};
#pragma unroll
    for (int it = 0; it < 8; it++) {
        float xk[4];
        *(float4*)xk = x4[it];
#pragma unroll
        for (int k = 0; k < 4; k++) {
            int c = it * 16 + q * 4 + k;
            float xv = xk[k];
            s += xv; s2 += xv * xv;
            float4 A0 = *(const float4*)&As[c * 12];
            float4 A1 = *(const float4*)&As[c * 12 + 4];
            dot[0] += xv * A0.x; dot[1] += xv * A0.y;
            dot[2] += xv * A0.z; dot[3] += xv * A0.w;
            dot[4] += xv * A1.x; dot[5] += xv * A1.y;
            dot[6] += xv * A1.z; dot[7] += xv * A1.w;
        }
    }
    s = quad_sum(s);
    s2 = quad_sum(s2);
#pragma unroll
    for (int h = 0; h < 8; h++) dot[h] = quad_sum(dot[h]);
    float mu = s * (1.0f / 128.0f);
    float var = s2 * (1.0f / 128.0f) - mu * mu;
    float rs = rsqrtf(var + 1e-5f);
    int h0 = q * 2;
#pragma unroll
    for (int u = 0; u < 2; u++) {
        int h = h0 + u;
        b2[h * 65536 + row] = rs * (dot[h] - mu * As[1536 + h]) + As[1544 + h];
    }
}

// ---------------- Kernel 4: per-channel softmax attention + gate -----------
__global__ __launch_bounds__(256) void attn_kernel(
    const float* __restrict__ q_t, const float* __restrict__ k_t,
    const float* __restrict__ v_t, const float* __restrict__ g_t,
    const float* __restrict__ b2, float* __restrict__ ao)
{
    __shared__ float k_sh[256][32];
    __shared__ float v_sh[256][32];
    int blk = blockIdx.x;
    int s = blk >> 6, h = (blk >> 3) & 7, it = blk & 7;
    int t = threadIdx.x;
    const float* kb = k_t + (size_t)(h * M_ROWS + s * N_RES) * D_DIM;
    const float* vb = v_t + (size_t)(h * M_ROWS + s * N_RES) * D_DIM;
    for (int idx = t; idx < 2048; idx += 256) {
        ((float4*)k_sh)[idx] = ((const float4*)kb)[idx];
        ((float4*)v_sh)[idx] = ((const float4*)vb)[idx];
    }
    __syncthreads();
    int jp = t & 3, dg = (t >> 2) & 7, li = t >> 5;
    int d0 = dg * 4;
    const float SCL2 = 0.17677669529663687f * LOG2E;  // 1/sqrt(32) * log2e
    int ig[4], mrow[4];
    float qs[4][4];
#pragma unroll
    for (int r = 0; r < 4; r++) {
        ig[r] = it * 32 + r * 8 + li;
        mrow[r] = s * N_RES + ig[r];
        float4 q4 = *(const float4*)&q_t[(size_t)(h * M_ROWS + mrow[r]) * D_DIM + d0];
        qs[r][0] = q4.x * SCL2; qs[r][1] = q4.y * SCL2;
        qs[r][2] = q4.z * SCL2; qs[r][3] = q4.w * SCL2;
    }
    float den[4][4] = {}, acc[4][4] = {};
    const float* bbase = b2 + h * 65536;
    for (int js4 = 0; js4 < 16; js4++) {
        float bb[4][4];
#pragma unroll
        for (int r = 0; r < 4; r++)
            *(float4*)&bb[r][0] =
                *(const float4*)&bbase[ig[r] * 256 + jp * 64 + js4 * 4];
#pragma unroll
        for (int u = 0; u < 4; u++) {
            int j = jp * 64 + js4 * 4 + u;
            float ka[4], va[4];
            *(float4*)ka = *(const float4*)&k_sh[j][d0];
            *(float4*)va = *(const float4*)&v_sh[j][d0];
#pragma unroll
            for (int r = 0; r < 4; r++) {
#pragma unroll
                for (int c = 0; c < 4; c++) {
                    float e = __builtin_amdgcn_exp2f(qs[r][c] * ka[c] + bb[r][u]);
                    den[r][c] += e;
                    acc[r][c] += e * va[c];
                }
            }
        }
    }
#pragma unroll
    for (int r = 0; r < 4; r++)
#pragma unroll
        for (int c = 0; c < 4; c++) {
            den[r][c] = quad_sum(den[r][c]);
            acc[r][c] = quad_sum(acc[r][c]);
        }
    if (jp == 0) {
#pragma unroll
        for (int r = 0; r < 4; r++) {
            float4 g4 = *(const float4*)&g_t[(size_t)(h * M_ROWS + mrow[r]) * D_DIM + d0];
            float4 o;
            o.x = g4.x * acc[r][0] / den[r][0];
            o.y = g4.y * acc[r][1] / den[r][1];
            o.z = g4.z * acc[r][2] / den[r][2];
            o.w = g4.w * acc[r][3] / den[r][3];
            *(float4*)&ao[(size_t)mrow[r] * HD + h * 32 + d0] = o;
        }
    }
}

extern "C" void kernel_launch(void* const* d_in, const int* in_sizes, int n_in,
                              void* d_out, int out_size, void* d_ws, size_t ws_size,
                              hipStream_t stream)
{
    const float* msa_rep   = (const float*)d_in[0];
    const float* pair_rep  = (const float*)d_in[1];
    const float* ln_w      = (const float*)d_in[2];
    const float* ln_b      = (const float*)d_in[3];
    const float* w_qkv     = (const float*)d_in[4];
    const float* ln_pair_w = (const float*)d_in[5];
    const float* ln_pair_b = (const float*)d_in[6];
    const float* w_b       = (const float*)d_in[7];
    const float* w_g       = (const float*)d_in[8];
    const float* w_out     = (const float*)d_in[9];
    const float* b_out     = (const float*)d_in[10];
    float* out = (float*)d_out;

    float* ws = (float*)d_ws;
    const size_t CH = 524288;     // 2048*256
    float* x    = ws + 0 * CH;
    float* q_t  = ws + 1 * CH;
    float* k_t  = ws + 2 * CH;
    float* v_t  = ws + 3 * CH;
    float* g_t  = ws + 4 * CH;
    float* b2   = ws + 5 * CH;
    float* ao   = ws + 6 * CH;
    float* Abuf = ws + 7 * CH;    // 1552 floats
    float* part = ws + 8 * CH;    // 4 x 2048*256 partials

    ln_msa_kernel<<<M_ROWS, 256, 0, stream>>>(msa_rep, ln_w, ln_b, x);

    xw_kernel<<<dim3(8, 32), 256, 0, stream>>>(
        x, w_qkv, w_g, q_t, k_t, v_t, g_t);

    pb_setup_kernel<<<1, 128, 0, stream>>>(ln_pair_w, ln_pair_b, w_b, Abuf);

    pair_bias_kernel<<<65536 / 64, 256, 0, stream>>>(pair_rep, Abuf, b2);

    attn_kernel<<<512, 256, 0, stream>>>(q_t, k_t, v_t, g_t, b2, ao);

    out_gemm_kernel<<<dim3(2, 32, 4), 256, 0, stream>>>(ao, w_out, part);

    reduce_out_kernel<<<512, 256, 0, stream>>>(part, b_out, out);
}

// Round 6
// 169.226 us; speedup vs baseline: 1.1291x; 1.1291x over previous
//
#include <hip/hip_runtime.h>
#include <math.h>

#define S_DIM 8
#define N_RES 256
#define MSA_DIM 256
#define PAIR_DIM 128
#define D_DIM 32
#define H_DIM 8
#define M_ROWS (S_DIM * N_RES)      // 2048
#define QKV_N (3 * H_DIM * D_DIM)   // 768
#define HD (H_DIM * D_DIM)          // 256
#define LOG2E 1.4426950408889634f

// ---- wave64 sum via DPP; total lands in lane 63
#define DPP_ADD(x, ctrl, rmask)                                                \
    x += __int_as_float(__builtin_amdgcn_update_dpp(                           \
        0, __float_as_int(x), (ctrl), (rmask), 0xf, true))

__device__ __forceinline__ float wave_sum63(float x) {
    DPP_ADD(x, 0x111, 0xf);   // row_shr:1
    DPP_ADD(x, 0x112, 0xf);   // row_shr:2
    DPP_ADD(x, 0x114, 0xf);   // row_shr:4
    DPP_ADD(x, 0x118, 0xf);   // row_shr:8
    DPP_ADD(x, 0x142, 0xa);   // row_bcast:15 -> rows 1,3
    DPP_ADD(x, 0x143, 0xc);   // row_bcast:31 -> rows 2,3
    return x;
}

// sum over the 4 lanes of a quad (all quad lanes end with the total)
__device__ __forceinline__ float quad_sum(float x) {
    x += __int_as_float(__builtin_amdgcn_update_dpp(
        0, __float_as_int(x), 0xB1, 0xf, 0xf, true));  // quad_perm [1,0,3,2]
    x += __int_as_float(__builtin_amdgcn_update_dpp(
        0, __float_as_int(x), 0x4E, 0xf, 0xf, true));  // quad_perm [2,3,0,1]
    return x;
}

// ---------------- Kernel 1: LayerNorm of msa rows -> x [2048,256] ----------
__global__ __launch_bounds__(256) void ln_msa_kernel(
    const float* __restrict__ msa, const float* __restrict__ w,
    const float* __restrict__ b, float* __restrict__ x)
{
    int row = blockIdx.x;
    int t = threadIdx.x;
    float v = msa[row * MSA_DIM + t];
    float s1 = wave_sum63(v);
    float s2 = wave_sum63(v * v);
    __shared__ float r1[4], r2[4];
    int wave = t >> 6, lane = t & 63;
    if (lane == 63) { r1[wave] = s1; r2[wave] = s2; }
    __syncthreads();
    float S1 = r1[0] + r1[1] + r1[2] + r1[3];
    float S2 = r2[0] + r2[1] + r2[2] + r2[3];
    float mu = S1 * (1.0f / 256.0f);
    float var = S2 * (1.0f / 256.0f) - mu * mu;
    float rs = rsqrtf(var + 1e-5f);
    x[row * MSA_DIM + t] = (v - mu) * rs * w[t] + b[t];
}

// ------- Kernel 2: fused qkv+g GEMM, dual-LDS, 64m x 128n, 4m x 8n/thread --
// grid (8, 32) = 256 blocks. bx<6 -> qkv (scatter q/k/v [h][m][d]); else gate.
// b-operand split as [tn*4] and [64+tn*4] (stride-4 -> 2-way LDS alias, free)
__global__ __launch_bounds__(256) void xw_kernel(
    const float* __restrict__ X, const float* __restrict__ Wqkv,
    const float* __restrict__ Wg, float* __restrict__ q_t,
    float* __restrict__ k_t, float* __restrict__ v_t, float* __restrict__ g_t)
{
    __shared__ float Xs[16][68];
    __shared__ float Ws[16][132];
    int t = threadIdx.x;
    int bx = blockIdx.x;
    int qkv_mode = (bx < 6);
    int n0 = bx * 128;
    const float* W = qkv_mode ? Wqkv : Wg;
    int Ncols = qkv_mode ? QKV_N : HD;
    int wn0 = qkv_mode ? n0 : n0 - QKV_N;
    int m0 = blockIdx.y * 64;
    int tm = t >> 4, tn = t & 15;
    int lxm = t >> 2, lxk = (t & 3) * 4;    // X loader: 1 float4/thread
    int lwk = t >> 4, lwn = (t & 15) * 8;   // W loader: 2 float4/thread
    float acc[4][8] = {};
    float4 xa = *(const float4*)&X[(m0 + lxm) * 256 + lxk];
    float4 w0 = *(const float4*)&W[(size_t)lwk * Ncols + wn0 + lwn];
    float4 w1 = *(const float4*)&W[(size_t)lwk * Ncols + wn0 + lwn + 4];
    for (int kt = 0; kt < 16; kt++) {
        __syncthreads();
        Xs[lxk + 0][lxm] = xa.x; Xs[lxk + 1][lxm] = xa.y;
        Xs[lxk + 2][lxm] = xa.z; Xs[lxk + 3][lxm] = xa.w;
        *(float4*)&Ws[lwk][lwn] = w0;
        *(float4*)&Ws[lwk][lwn + 4] = w1;
        __syncthreads();
        if (kt < 15) {
            int kb = (kt + 1) * 16;
            xa = *(const float4*)&X[(m0 + lxm) * 256 + kb + lxk];
            w0 = *(const float4*)&W[(size_t)(kb + lwk) * Ncols + wn0 + lwn];
            w1 = *(const float4*)&W[(size_t)(kb + lwk) * Ncols + wn0 + lwn + 4];
        }
#pragma unroll
        for (int kk = 0; kk < 16; kk++) {
            float a[4], b[8];
            *(float4*)a = *(const float4*)&Xs[kk][tm * 4];
            *(float4*)&b[0] = *(const float4*)&Ws[kk][tn * 4];
            *(float4*)&b[4] = *(const float4*)&Ws[kk][64 + tn * 4];
#pragma unroll
            for (int i = 0; i < 4; i++)
#pragma unroll
                for (int u = 0; u < 8; u++) acc[i][u] += a[i] * b[u];
        }
    }
#pragma unroll
    for (int i = 0; i < 4; i++) {
        int mm = m0 + tm * 4 + i;
#pragma unroll
        for (int u = 0; u < 8; u++) {
            float c = acc[i][u];
            int nn = n0 + (u >> 2) * 64 + tn * 4 + (u & 3);
            if (qkv_mode) {
                int chunk = nn >> 8, r = nn & 255, d = r >> 3, h = r & 7;
                float* dst = (chunk == 0) ? q_t : ((chunk == 1) ? k_t : v_t);
                dst[(h * M_ROWS + mm) * D_DIM + d] = c;
            } else {
                int gn = nn - QKV_N;
                int d = gn >> 3, h = gn & 7;
                g_t[(h * M_ROWS + mm) * D_DIM + d] = 1.0f / (1.0f + __expf(-c));
            }
        }
    }
}

// ------- Kernel 2b: out GEMM, dual-LDS, K-split 4 -> f32 partials ----------
// ao layout [m][h*32+d]; w_out row for col k is (k&31)*8+(k>>5)
__global__ __launch_bounds__(256) void out_gemm_kernel(
    const float* __restrict__ X, const float* __restrict__ W,
    float* __restrict__ part)
{
    __shared__ float Xs[16][68];
    __shared__ float Ws[16][132];
    int t = threadIdx.x;
    int n0 = blockIdx.x * 128;
    int m0 = blockIdx.y * 64;
    int k0g = blockIdx.z * 64;
    int tm = t >> 4, tn = t & 15;
    int lxm = t >> 2, lxk = (t & 3) * 4;
    int lwk = t >> 4, lwn = (t & 15) * 8;
    float acc[4][8] = {};
    int wr0 = ((k0g + lwk) & 31) * 8 + ((k0g + lwk) >> 5);
    float4 xa = *(const float4*)&X[(m0 + lxm) * 256 + k0g + lxk];
    float4 w0 = *(const float4*)&W[(size_t)wr0 * 256 + n0 + lwn];
    float4 w1 = *(const float4*)&W[(size_t)wr0 * 256 + n0 + lwn + 4];
    for (int kt = 0; kt < 4; kt++) {
        __syncthreads();
        Xs[lxk + 0][lxm] = xa.x; Xs[lxk + 1][lxm] = xa.y;
        Xs[lxk + 2][lxm] = xa.z; Xs[lxk + 3][lxm] = xa.w;
        *(float4*)&Ws[lwk][lwn] = w0;
        *(float4*)&Ws[lwk][lwn + 4] = w1;
        __syncthreads();
        if (kt < 3) {
            int kb = k0g + (kt + 1) * 16;
            int wrow = ((kb + lwk) & 31) * 8 + ((kb + lwk) >> 5);
            xa = *(const float4*)&X[(m0 + lxm) * 256 + kb + lxk];
            w0 = *(const float4*)&W[(size_t)wrow * 256 + n0 + lwn];
            w1 = *(const float4*)&W[(size_t)wrow * 256 + n0 + lwn + 4];
        }
#pragma unroll
        for (int kk = 0; kk < 16; kk++) {
            float a[4], b[8];
            *(float4*)a = *(const float4*)&Xs[kk][tm * 4];
            *(float4*)&b[0] = *(const float4*)&Ws[kk][tn * 4];
            *(float4*)&b[4] = *(const float4*)&Ws[kk][64 + tn * 4];
#pragma unroll
            for (int i = 0; i < 4; i++)
#pragma unroll
                for (int u = 0; u < 8; u++) acc[i][u] += a[i] * b[u];
        }
    }
    float* pb = part + (size_t)blockIdx.z * (M_ROWS * 256);
#pragma unroll
    for (int i = 0; i < 4; i++) {
        int mm = m0 + tm * 4 + i;
        *(float4*)&pb[mm * 256 + n0 + tn * 4] = *(float4*)&acc[i][0];
        *(float4*)&pb[mm * 256 + n0 + 64 + tn * 4] = *(float4*)&acc[i][4];
    }
}

// ------- Kernel 2c: reduce 4 partials + bias -> out ------------------------
__global__ __launch_bounds__(256) void reduce_out_kernel(
    const float* __restrict__ part, const float* __restrict__ bias,
    float* __restrict__ out)
{
    int idx = blockIdx.x * 256 + threadIdx.x;   // float4 index
    int e = idx * 4;
    int n = e & 255;
    float4 p0 = *(const float4*)&part[e];
    float4 p1 = *(const float4*)&part[e + M_ROWS * 256];
    float4 p2 = *(const float4*)&part[e + 2 * M_ROWS * 256];
    float4 p3 = *(const float4*)&part[e + 3 * M_ROWS * 256];
    float4 bb = *(const float4*)&bias[n];
    float4 o;
    o.x = p0.x + p1.x + p2.x + p3.x + bb.x;
    o.y = p0.y + p1.y + p2.y + p3.y + bb.y;
    o.z = p0.z + p1.z + p2.z + p3.z + bb.z;
    o.w = p0.w + p1.w + p2.w + p3.w + bb.w;
    *(float4*)&out[e] = o;
}

// ------- Kernel 3a: setup A'[c][h]=lw*wb*log2e [128][12], S'[8], C'[8] -----
__global__ __launch_bounds__(128) void pb_setup_kernel(
    const float* __restrict__ lw, const float* __restrict__ lb,
    const float* __restrict__ wb, float* __restrict__ Abuf)
{
    __shared__ float P[128][8], Q[128][8];
    int c = threadIdx.x;
    float lwc = lw[c], lbc = lb[c];
#pragma unroll
    for (int h = 0; h < 8; h++) {
        float w = wb[c * 8 + h];
        float a = lwc * w;
        P[c][h] = a;
        Q[c][h] = lbc * w;
        Abuf[c * 12 + h] = a * LOG2E;
    }
    __syncthreads();
    if (c < 8) {
        float s = 0, cc = 0;
        for (int k = 0; k < 128; k++) { s += P[k][c]; cc += Q[k][c]; }
        Abuf[1536 + c] = s * LOG2E;     // S'
        Abuf[1544 + c] = cc * LOG2E;    // C'
    }
}

// ------- Kernel 3b: pair bias b2[h][i][j] = log2e*(LN(pair[i,j,:]) @ w_b) --
__global__ __launch_bounds__(256) void pair_bias_kernel(
    const float* __restrict__ pair, const float* __restrict__ Abuf,
    float* __restrict__ b2)
{
    __shared__ __align__(16) float As[1552];   // [128][12] + S'[8] + C'[8]
    int t = threadIdx.x;
    for (int idx = t; idx < 388; idx += 256)
        ((float4*)As)[idx] = ((const float4*)Abuf)[idx];
    __syncthreads();
    int row = blockIdx.x * 64 + (t >> 2);
    int q = t & 3;
    const float* in = pair + (size_t)row * PAIR_DIM;
    float4 x4[8];
#pragma unroll
    for (int it = 0; it < 8; it++)
        x4[it] = *(const float4*)&in[it * 16 + q * 4];
    float s = 0, s2 = 0;
    float dot[8] = {};
#pragma unroll
    for (int it = 0; it < 8; it++) {
        float xk[4];
        *(float4*)xk = x4[it];
#pragma unroll
        for (int k = 0; k < 4; k++) {
            int c = it * 16 + q * 4 + k;
            float xv = xk[k];
            s += xv; s2 += xv * xv;
            float4 A0 = *(const float4*)&As[c * 12];
            float4 A1 = *(const float4*)&As[c * 12 + 4];
            dot[0] += xv * A0.x; dot[1] += xv * A0.y;
            dot[2] += xv * A0.z; dot[3] += xv * A0.w;
            dot[4] += xv * A1.x; dot[5] += xv * A1.y;
            dot[6] += xv * A1.z; dot[7] += xv * A1.w;
        }
    }
    s = quad_sum(s);
    s2 = quad_sum(s2);
#pragma unroll
    for (int h = 0; h < 8; h++) dot[h] = quad_sum(dot[h]);
    float mu = s * (1.0f / 128.0f);
    float var = s2 * (1.0f / 128.0f) - mu * mu;
    float rs = rsqrtf(var + 1e-5f);
    int h0 = q * 2;
#pragma unroll
    for (int u = 0; u < 2; u++) {
        int h = h0 + u;
        b2[h * 65536 + row] = rs * (dot[h] - mu * As[1536 + h]) + As[1544 + h];
    }
}

// ---------------- Kernel 4: per-channel softmax attention + gate -----------
__global__ __launch_bounds__(256) void attn_kernel(
    const float* __restrict__ q_t, const float* __restrict__ k_t,
    const float* __restrict__ v_t, const float* __restrict__ g_t,
    const float* __restrict__ b2, float* __restrict__ ao)
{
    __shared__ float k_sh[256][32];
    __shared__ float v_sh[256][32];
    int blk = blockIdx.x;
    int s = blk >> 6, h = (blk >> 3) & 7, it = blk & 7;
    int t = threadIdx.x;
    const float* kb = k_t + (size_t)(h * M_ROWS + s * N_RES) * D_DIM;
    const float* vb = v_t + (size_t)(h * M_ROWS + s * N_RES) * D_DIM;
    for (int idx = t; idx < 2048; idx += 256) {
        ((float4*)k_sh)[idx] = ((const float4*)kb)[idx];
        ((float4*)v_sh)[idx] = ((const float4*)vb)[idx];
    }
    __syncthreads();
    int jp = t & 3, dg = (t >> 2) & 7, li = t >> 5;
    int d0 = dg * 4;
    const float SCL2 = 0.17677669529663687f * LOG2E;  // 1/sqrt(32) * log2e
    int ig[4], mrow[4];
    float qs[4][4];
#pragma unroll
    for (int r = 0; r < 4; r++) {
        ig[r] = it * 32 + r * 8 + li;
        mrow[r] = s * N_RES + ig[r];
        float4 q4 = *(const float4*)&q_t[(size_t)(h * M_ROWS + mrow[r]) * D_DIM + d0];
        qs[r][0] = q4.x * SCL2; qs[r][1] = q4.y * SCL2;
        qs[r][2] = q4.z * SCL2; qs[r][3] = q4.w * SCL2;
    }
    float den[4][4] = {}, acc[4][4] = {};
    const float* bbase = b2 + h * 65536;
    for (int js4 = 0; js4 < 16; js4++) {
        float bb[4][4];
#pragma unroll
        for (int r = 0; r < 4; r++)
            *(float4*)&bb[r][0] =
                *(const float4*)&bbase[ig[r] * 256 + jp * 64 + js4 * 4];
#pragma unroll
        for (int u = 0; u < 4; u++) {
            int j = jp * 64 + js4 * 4 + u;
            float ka[4], va[4];
            *(float4*)ka = *(const float4*)&k_sh[j][d0];
            *(float4*)va = *(const float4*)&v_sh[j][d0];
#pragma unroll
            for (int r = 0; r < 4; r++) {
#pragma unroll
                for (int c = 0; c < 4; c++) {
                    float e = __builtin_amdgcn_exp2f(qs[r][c] * ka[c] + bb[r][u]);
                    den[r][c] += e;
                    acc[r][c] += e * va[c];
                }
            }
        }
    }
#pragma unroll
    for (int r = 0; r < 4; r++)
#pragma unroll
        for (int c = 0; c < 4; c++) {
            den[r][c] = quad_sum(den[r][c]);
            acc[r][c] = quad_sum(acc[r][c]);
        }
    if (jp == 0) {
#pragma unroll
        for (int r = 0; r < 4; r++) {
            float4 g4 = *(const float4*)&g_t[(size_t)(h * M_ROWS + mrow[r]) * D_DIM + d0];
            float4 o;
            o.x = g4.x * acc[r][0] / den[r][0];
            o.y = g4.y * acc[r][1] / den[r][1];
            o.z = g4.z * acc[r][2] / den[r][2];
            o.w = g4.w * acc[r][3] / den[r][3];
            *(float4*)&ao[(size_t)mrow[r] * HD + h * 32 + d0] = o;
        }
    }
}

extern "C" void kernel_launch(void* const* d_in, const int* in_sizes, int n_in,
                              void* d_out, int out_size, void* d_ws, size_t ws_size,
                              hipStream_t stream)
{
    const float* msa_rep   = (const float*)d_in[0];
    const float* pair_rep  = (const float*)d_in[1];
    const float* ln_w      = (const float*)d_in[2];
    const float* ln_b      = (const float*)d_in[3];
    const float* w_qkv     = (const float*)d_in[4];
    const float* ln_pair_w = (const float*)d_in[5];
    const float* ln_pair_b = (const float*)d_in[6];
    const float* w_b       = (const float*)d_in[7];
    const float* w_g       = (const float*)d_in[8];
    const float* w_out     = (const float*)d_in[9];
    const float* b_out     = (const float*)d_in[10];
    float* out = (float*)d_out;

    float* ws = (float*)d_ws;
    const size_t CH = 524288;     // 2048*256
    float* x    = ws + 0 * CH;
    float* q_t  = ws + 1 * CH;
    float* k_t  = ws + 2 * CH;
    float* v_t  = ws + 3 * CH;
    float* g_t  = ws + 4 * CH;
    float* b2   = ws + 5 * CH;
    float* ao   = ws + 6 * CH;
    float* Abuf = ws + 7 * CH;    // 1552 floats
    float* part = ws + 8 * CH;    // 4 x 2048*256 partials

    ln_msa_kernel<<<M_ROWS, 256, 0, stream>>>(msa_rep, ln_w, ln_b, x);

    xw_kernel<<<dim3(8, 32), 256, 0, stream>>>(
        x, w_qkv, w_g, q_t, k_t, v_t, g_t);

    pb_setup_kernel<<<1, 128, 0, stream>>>(ln_pair_w, ln_pair_b, w_b, Abuf);

    pair_bias_kernel<<<65536 / 64, 256, 0, stream>>>(pair_rep, Abuf, b2);

    attn_kernel<<<512, 256, 0, stream>>>(q_t, k_t, v_t, g_t, b2, ao);

    out_gemm_kernel<<<dim3(2, 32, 4), 256, 0, stream>>>(ao, w_out, part);

    reduce_out_kernel<<<512, 256, 0, stream>>>(part, b_out, out);
}

// Round 7
// 154.742 us; speedup vs baseline: 1.2348x; 1.0936x over previous
//
#include <hip/hip_runtime.h>
#include <math.h>

#define S_DIM 8
#define N_RES 256
#define MSA_DIM 256
#define PAIR_DIM 128
#define D_DIM 32
#define H_DIM 8
#define M_ROWS (S_DIM * N_RES)      // 2048
#define QKV_N (3 * H_DIM * D_DIM)   // 768
#define HD (H_DIM * D_DIM)          // 256
#define XW_N 1024                   // qkv(768) + gate(256)
#define LOG2E 1.4426950408889634f

typedef __attribute__((ext_vector_type(8))) short short8;
typedef __attribute__((ext_vector_type(4))) float floatx4;

// ---- wave64 sum via DPP; total lands in lane 63
#define DPP_ADD(x, ctrl, rmask)                                                \
    x += __int_as_float(__builtin_amdgcn_update_dpp(                           \
        0, __float_as_int(x), (ctrl), (rmask), 0xf, true))

__device__ __forceinline__ float wave_sum63(float x) {
    DPP_ADD(x, 0x111, 0xf);
    DPP_ADD(x, 0x112, 0xf);
    DPP_ADD(x, 0x114, 0xf);
    DPP_ADD(x, 0x118, 0xf);
    DPP_ADD(x, 0x142, 0xa);
    DPP_ADD(x, 0x143, 0xc);
    return x;
}

__device__ __forceinline__ float quad_sum(float x) {
    x += __int_as_float(__builtin_amdgcn_update_dpp(
        0, __float_as_int(x), 0xB1, 0xf, 0xf, true));
    x += __int_as_float(__builtin_amdgcn_update_dpp(
        0, __float_as_int(x), 0x4E, 0xf, 0xf, true));
    return x;
}

// round-to-nearest fp32 -> bf16 bits
__device__ __forceinline__ unsigned short bf16rn(float v) {
    unsigned u = __float_as_uint(v);
    return (unsigned short)((u + 0x7FFF + ((u >> 16) & 1)) >> 16);
}

// ---------------- Kernel 1: LayerNorm -> xhi/xlo bf16 [2048,256] -----------
__global__ __launch_bounds__(256) void ln_msa_kernel(
    const float* __restrict__ msa, const float* __restrict__ w,
    const float* __restrict__ b, unsigned short* __restrict__ xhi,
    unsigned short* __restrict__ xlo)
{
    int row = blockIdx.x;
    int t = threadIdx.x;
    float v = msa[row * MSA_DIM + t];
    float s1 = wave_sum63(v);
    float s2 = wave_sum63(v * v);
    __shared__ float r1[4], r2[4];
    int wave = t >> 6, lane = t & 63;
    if (lane == 63) { r1[wave] = s1; r2[wave] = s2; }
    __syncthreads();
    float S1 = r1[0] + r1[1] + r1[2] + r1[3];
    float S2 = r2[0] + r2[1] + r2[2] + r2[3];
    float mu = S1 * (1.0f / 256.0f);
    float var = S2 * (1.0f / 256.0f) - mu * mu;
    float rs = rsqrtf(var + 1e-5f);
    float y = (v - mu) * rs * w[t] + b[t];
    unsigned short h = bf16rn(y);
    float hf = __uint_as_float((unsigned)h << 16);
    unsigned short l = bf16rn(y - hf);
    xhi[row * 256 + t] = h;
    xlo[row * 256 + t] = l;
}

// ------- Kernel 1b: W split+transpose: whiT/wloT [1024 n][256 k] bf16 ------
// logical W[k][n]: n<768 -> w_qkv, n>=768 -> w_g
__global__ __launch_bounds__(256) void wconv_kernel(
    const float* __restrict__ w_qkv, const float* __restrict__ w_g,
    unsigned short* __restrict__ whiT, unsigned short* __restrict__ wloT)
{
    int id = blockIdx.x * 256 + threadIdx.x;   // 32768 ids
    int n = id >> 5, oct = id & 31;
    int k0 = oct * 8;
    const float* src;
    int stride;
    if (n < QKV_N) { src = w_qkv + n; stride = QKV_N; }
    else           { src = w_g + (n - QKV_N); stride = HD; }
    unsigned short h8[8], l8[8];
#pragma unroll
    for (int j = 0; j < 8; j++) {
        float v = src[(size_t)(k0 + j) * stride];
        unsigned short h = bf16rn(v);
        float hf = __uint_as_float((unsigned)h << 16);
        h8[j] = h;
        l8[j] = bf16rn(v - hf);
    }
    *(short8*)&whiT[n * 256 + k0] = *(short8*)h8;
    *(short8*)&wloT[n * 256 + k0] = *(short8*)l8;
}

// ------- Kernel 2: xw GEMM via bf16x3 MFMA ---------------------------------
// C = xhi@Whi + xlo@Whi + xhi@Wlo   (K' = 3*256, BK=64 -> 12 rounds)
// block: 64m x 128n, 4 waves as 2x2 of (32m x 64n); grid (8, 32)
__global__ __launch_bounds__(256) void xw_mfma_kernel(
    const unsigned short* __restrict__ xhi, const unsigned short* __restrict__ xlo,
    const unsigned short* __restrict__ whiT, const unsigned short* __restrict__ wloT,
    float* __restrict__ q_t, float* __restrict__ k_t,
    float* __restrict__ v_t, float* __restrict__ g_t)
{
    __shared__ unsigned short As[64 * 72];    // [m][k] pad 72
    __shared__ unsigned short Bs[128 * 72];   // [n][k] pad 72
    __shared__ float Cs[64 * 132];            // [m][n] pad 132
    int t = threadIdx.x;
    int n0 = blockIdx.x * 128, m0 = blockIdx.y * 64;
    int w = t >> 6, L = t & 63;
    int wm = (w & 1) * 32, wn = (w >> 1) * 64;
    int l15 = L & 15, l4 = L >> 4;

    // staging indices
    int alm = t >> 3, alk = (t & 7) * 8;     // A: rows alm, alm+32
    floatx4 acc[2][4];
#pragma unroll
    for (int a = 0; a < 2; a++)
#pragma unroll
        for (int b = 0; b < 4; b++) acc[a][b] = (floatx4){0, 0, 0, 0};

    const unsigned short* Asrc = xhi;
    const unsigned short* Bsrc = whiT;
    short8 pa0 = *(const short8*)&Asrc[(m0 + alm) * 256 + alk];
    short8 pa1 = *(const short8*)&Asrc[(m0 + alm + 32) * 256 + alk];
    short8 pb[4];
#pragma unroll
    for (int j = 0; j < 4; j++) {
        int id = t + 256 * j;
        int bn = id >> 3, bc = (id & 7) * 8;
        pb[j] = *(const short8*)&Bsrc[(n0 + bn) * 256 + bc];
    }

    for (int r = 0; r < 12; r++) {
        __syncthreads();
        *(short8*)&As[alm * 72 + alk] = pa0;
        *(short8*)&As[(alm + 32) * 72 + alk] = pa1;
#pragma unroll
        for (int j = 0; j < 4; j++) {
            int id = t + 256 * j;
            int bn = id >> 3, bc = (id & 7) * 8;
            *(short8*)&Bs[bn * 72 + bc] = pb[j];
        }
        __syncthreads();
        if (r < 11) {
            int rn = r + 1;
            int seg = rn >> 2, kb = (rn & 3) * 64;
            const unsigned short* An = (seg == 1) ? xlo : xhi;
            const unsigned short* Bn = (seg == 2) ? wloT : whiT;
            pa0 = *(const short8*)&An[(m0 + alm) * 256 + kb + alk];
            pa1 = *(const short8*)&An[(m0 + alm + 32) * 256 + kb + alk];
#pragma unroll
            for (int j = 0; j < 4; j++) {
                int id = t + 256 * j;
                int bn = id >> 3, bc = (id & 7) * 8;
                pb[j] = *(const short8*)&Bn[(n0 + bn) * 256 + kb + bc];
            }
        }
#pragma unroll
        for (int ks = 0; ks < 2; ks++) {
            int ko = ks * 32 + l4 * 8;
            short8 af[2], bf[4];
#pragma unroll
            for (int a = 0; a < 2; a++)
                af[a] = *(short8*)&As[(wm + a * 16 + l15) * 72 + ko];
#pragma unroll
            for (int b = 0; b < 4; b++)
                bf[b] = *(short8*)&Bs[(wn + b * 16 + l15) * 72 + ko];
#pragma unroll
            for (int a = 0; a < 2; a++)
#pragma unroll
                for (int b = 0; b < 4; b++)
                    acc[a][b] = __builtin_amdgcn_mfma_f32_16x16x32_bf16(
                        af[a], bf[b], acc[a][b], 0, 0, 0);
        }
    }

    // epilogue: frags -> Cs -> coalesced scatter
#pragma unroll
    for (int a = 0; a < 2; a++)
#pragma unroll
        for (int b = 0; b < 4; b++) {
            int nl = wn + b * 16 + l15;
#pragma unroll
            for (int rg = 0; rg < 4; rg++) {
                int ml = wm + a * 16 + l4 * 4 + rg;
                Cs[ml * 132 + nl] = acc[a][b][rg];
            }
        }
    __syncthreads();
    int qkv_mode = (n0 < QKV_N);
    int chunk = n0 >> 8;
    int dbase = (n0 & 255) >> 3;   // 0 or 16
#pragma unroll
    for (int j = 0; j < 8; j++) {
        int id = t + 256 * j;              // 2048 float4-groups
        int m = id >> 5;
        int h = (id >> 2) & 7;
        int dq = id & 3;
        float vals[4];
#pragma unroll
        for (int jj = 0; jj < 4; jj++)
            vals[jj] = Cs[m * 132 + (dq * 4 + jj) * 8 + h];
        int mm = m0 + m;
        int daddr = dbase + dq * 4;
        if (qkv_mode) {
            float* dst = (chunk == 0) ? q_t : ((chunk == 1) ? k_t : v_t);
            *(float4*)&dst[(size_t)(h * M_ROWS + mm) * D_DIM + daddr] =
                *(float4*)vals;
        } else {
            float4 o;
            o.x = 1.0f / (1.0f + __expf(-vals[0]));
            o.y = 1.0f / (1.0f + __expf(-vals[1]));
            o.z = 1.0f / (1.0f + __expf(-vals[2]));
            o.w = 1.0f / (1.0f + __expf(-vals[3]));
            *(float4*)&g_t[(size_t)(h * M_ROWS + mm) * D_DIM + daddr] = o;
        }
    }
}

// ------- Kernel 2b: out GEMM, dual-LDS, K-split 4 -> f32 partials ----------
__global__ __launch_bounds__(256) void out_gemm_kernel(
    const float* __restrict__ X, const float* __restrict__ W,
    float* __restrict__ part)
{
    __shared__ float Xs[16][68];
    __shared__ float Ws[16][132];
    int t = threadIdx.x;
    int n0 = blockIdx.x * 128;
    int m0 = blockIdx.y * 64;
    int k0g = blockIdx.z * 64;
    int tm = t >> 4, tn = t & 15;
    int lxm = t >> 2, lxk = (t & 3) * 4;
    int lwk = t >> 4, lwn = (t & 15) * 8;
    float acc[4][8] = {};
    int wr0 = ((k0g + lwk) & 31) * 8 + ((k0g + lwk) >> 5);
    float4 xa = *(const float4*)&X[(m0 + lxm) * 256 + k0g + lxk];
    float4 w0 = *(const float4*)&W[(size_t)wr0 * 256 + n0 + lwn];
    float4 w1 = *(const float4*)&W[(size_t)wr0 * 256 + n0 + lwn + 4];
    for (int kt = 0; kt < 4; kt++) {
        __syncthreads();
        Xs[lxk + 0][lxm] = xa.x; Xs[lxk + 1][lxm] = xa.y;
        Xs[lxk + 2][lxm] = xa.z; Xs[lxk + 3][lxm] = xa.w;
        *(float4*)&Ws[lwk][lwn] = w0;
        *(float4*)&Ws[lwk][lwn + 4] = w1;
        __syncthreads();
        if (kt < 3) {
            int kb = k0g + (kt + 1) * 16;
            int wrow = ((kb + lwk) & 31) * 8 + ((kb + lwk) >> 5);
            xa = *(const float4*)&X[(m0 + lxm) * 256 + kb + lxk];
            w0 = *(const float4*)&W[(size_t)wrow * 256 + n0 + lwn];
            w1 = *(const float4*)&W[(size_t)wrow * 256 + n0 + lwn + 4];
        }
#pragma unroll
        for (int kk = 0; kk < 16; kk++) {
            float a[4], b[8];
            *(float4*)a = *(const float4*)&Xs[kk][tm * 4];
            *(float4*)&b[0] = *(const float4*)&Ws[kk][tn * 4];
            *(float4*)&b[4] = *(const float4*)&Ws[kk][64 + tn * 4];
#pragma unroll
            for (int i = 0; i < 4; i++)
#pragma unroll
                for (int u = 0; u < 8; u++) acc[i][u] += a[i] * b[u];
        }
    }
    float* pb = part + (size_t)blockIdx.z * (M_ROWS * 256);
#pragma unroll
    for (int i = 0; i < 4; i++) {
        int mm = m0 + tm * 4 + i;
        *(float4*)&pb[mm * 256 + n0 + tn * 4] = *(float4*)&acc[i][0];
        *(float4*)&pb[mm * 256 + n0 + 64 + tn * 4] = *(float4*)&acc[i][4];
    }
}

// ------- Kernel 2c: reduce 4 partials + bias -> out ------------------------
__global__ __launch_bounds__(256) void reduce_out_kernel(
    const float* __restrict__ part, const float* __restrict__ bias,
    float* __restrict__ out)
{
    int idx = blockIdx.x * 256 + threadIdx.x;
    int e = idx * 4;
    int n = e & 255;
    float4 p0 = *(const float4*)&part[e];
    float4 p1 = *(const float4*)&part[e + M_ROWS * 256];
    float4 p2 = *(const float4*)&part[e + 2 * M_ROWS * 256];
    float4 p3 = *(const float4*)&part[e + 3 * M_ROWS * 256];
    float4 bb = *(const float4*)&bias[n];
    float4 o;
    o.x = p0.x + p1.x + p2.x + p3.x + bb.x;
    o.y = p0.y + p1.y + p2.y + p3.y + bb.y;
    o.z = p0.z + p1.z + p2.z + p3.z + bb.z;
    o.w = p0.w + p1.w + p2.w + p3.w + bb.w;
    *(float4*)&out[e] = o;
}

// ------- Kernel 3a: setup A'[c][h]=lw*wb*log2e [128][12], S'[8], C'[8] -----
__global__ __launch_bounds__(128) void pb_setup_kernel(
    const float* __restrict__ lw, const float* __restrict__ lb,
    const float* __restrict__ wb, float* __restrict__ Abuf)
{
    __shared__ float P[128][8], Q[128][8];
    int c = threadIdx.x;
    float lwc = lw[c], lbc = lb[c];
#pragma unroll
    for (int h = 0; h < 8; h++) {
        float w = wb[c * 8 + h];
        float a = lwc * w;
        P[c][h] = a;
        Q[c][h] = lbc * w;
        Abuf[c * 12 + h] = a * LOG2E;
    }
    __syncthreads();
    if (c < 8) {
        float s = 0, cc = 0;
        for (int k = 0; k < 128; k++) { s += P[k][c]; cc += Q[k][c]; }
        Abuf[1536 + c] = s * LOG2E;
        Abuf[1544 + c] = cc * LOG2E;
    }
}

// ------- Kernel 3b: pair bias b2[h][i][j] = log2e*(LN(pair) @ w_b) ---------
__global__ __launch_bounds__(256) void pair_bias_kernel(
    const float* __restrict__ pair, const float* __restrict__ Abuf,
    float* __restrict__ b2)
{
    __shared__ __align__(16) float As[1552];
    int t = threadIdx.x;
    for (int idx = t; idx < 388; idx += 256)
        ((float4*)As)[idx] = ((const float4*)Abuf)[idx];
    __syncthreads();
    int row = blockIdx.x * 64 + (t >> 2);
    int q = t & 3;
    const float* in = pair + (size_t)row * PAIR_DIM;
    float4 x4[8];
#pragma unroll
    for (int it = 0; it < 8; it++)
        x4[it] = *(const float4*)&in[it * 16 + q * 4];
    float s = 0, s2 = 0;
    float dot[8] = {};
#pragma unroll
    for (int it = 0; it < 8; it++) {
        float xk[4];
        *(float4*)xk = x4[it];
#pragma unroll
        for (int k = 0; k < 4; k++) {
            int c = it * 16 + q * 4 + k;
            float xv = xk[k];
            s += xv; s2 += xv * xv;
            float4 A0 = *(const float4*)&As[c * 12];
            float4 A1 = *(const float4*)&As[c * 12 + 4];
            dot[0] += xv * A0.x; dot[1] += xv * A0.y;
            dot[2] += xv * A0.z; dot[3] += xv * A0.w;
            dot[4] += xv * A1.x; dot[5] += xv * A1.y;
            dot[6] += xv * A1.z; dot[7] += xv * A1.w;
        }
    }
    s = quad_sum(s);
    s2 = quad_sum(s2);
#pragma unroll
    for (int h = 0; h < 8; h++) dot[h] = quad_sum(dot[h]);
    float mu = s * (1.0f / 128.0f);
    float var = s2 * (1.0f / 128.0f) - mu * mu;
    float rs = rsqrtf(var + 1e-5f);
    int h0 = q * 2;
#pragma unroll
    for (int u = 0; u < 2; u++) {
        int h = h0 + u;
        b2[h * 65536 + row] = rs * (dot[h] - mu * As[1536 + h]) + As[1544 + h];
    }
}

// ---------------- Kernel 4: per-channel softmax attention + gate -----------
__global__ __launch_bounds__(256) void attn_kernel(
    const float* __restrict__ q_t, const float* __restrict__ k_t,
    const float* __restrict__ v_t, const float* __restrict__ g_t,
    const float* __restrict__ b2, float* __restrict__ ao)
{
    __shared__ float k_sh[256][32];
    __shared__ float v_sh[256][32];
    int blk = blockIdx.x;
    int s = blk >> 6, h = (blk >> 3) & 7, it = blk & 7;
    int t = threadIdx.x;
    const float* kb = k_t + (size_t)(h * M_ROWS + s * N_RES) * D_DIM;
    const float* vb = v_t + (size_t)(h * M_ROWS + s * N_RES) * D_DIM;
    for (int idx = t; idx < 2048; idx += 256) {
        ((float4*)k_sh)[idx] = ((const float4*)kb)[idx];
        ((float4*)v_sh)[idx] = ((const float4*)vb)[idx];
    }
    __syncthreads();
    int jp = t & 3, dg = (t >> 2) & 7, li = t >> 5;
    int d0 = dg * 4;
    const float SCL2 = 0.17677669529663687f * LOG2E;
    int ig[4], mrow[4];
    float qs[4][4];
#pragma unroll
    for (int r = 0; r < 4; r++) {
        ig[r] = it * 32 + r * 8 + li;
        mrow[r] = s * N_RES + ig[r];
        float4 q4 = *(const float4*)&q_t[(size_t)(h * M_ROWS + mrow[r]) * D_DIM + d0];
        qs[r][0] = q4.x * SCL2; qs[r][1] = q4.y * SCL2;
        qs[r][2] = q4.z * SCL2; qs[r][3] = q4.w * SCL2;
    }
    float den[4][4] = {}, acc[4][4] = {};
    const float* bbase = b2 + h * 65536;
    for (int js4 = 0; js4 < 16; js4++) {
        float bb[4][4];
#pragma unroll
        for (int r = 0; r < 4; r++)
            *(float4*)&bb[r][0] =
                *(const float4*)&bbase[ig[r] * 256 + jp * 64 + js4 * 4];
#pragma unroll
        for (int u = 0; u < 4; u++) {
            int j = jp * 64 + js4 * 4 + u;
            float ka[4], va[4];
            *(float4*)ka = *(const float4*)&k_sh[j][d0];
            *(float4*)va = *(const float4*)&v_sh[j][d0];
#pragma unroll
            for (int r = 0; r < 4; r++) {
#pragma unroll
                for (int c = 0; c < 4; c++) {
                    float e = __builtin_amdgcn_exp2f(qs[r][c] * ka[c] + bb[r][u]);
                    den[r][c] += e;
                    acc[r][c] += e * va[c];
                }
            }
        }
    }
#pragma unroll
    for (int r = 0; r < 4; r++)
#pragma unroll
        for (int c = 0; c < 4; c++) {
            den[r][c] = quad_sum(den[r][c]);
            acc[r][c] = quad_sum(acc[r][c]);
        }
    if (jp == 0) {
#pragma unroll
        for (int r = 0; r < 4; r++) {
            float4 g4 = *(const float4*)&g_t[(size_t)(h * M_ROWS + mrow[r]) * D_DIM + d0];
            float4 o;
            o.x = g4.x * acc[r][0] / den[r][0];
            o.y = g4.y * acc[r][1] / den[r][1];
            o.z = g4.z * acc[r][2] / den[r][2];
            o.w = g4.w * acc[r][3] / den[r][3];
            *(float4*)&ao[(size_t)mrow[r] * HD + h * 32 + d0] = o;
        }
    }
}

extern "C" void kernel_launch(void* const* d_in, const int* in_sizes, int n_in,
                              void* d_out, int out_size, void* d_ws, size_t ws_size,
                              hipStream_t stream)
{
    const float* msa_rep   = (const float*)d_in[0];
    const float* pair_rep  = (const float*)d_in[1];
    const float* ln_w      = (const float*)d_in[2];
    const float* ln_b      = (const float*)d_in[3];
    const float* w_qkv     = (const float*)d_in[4];
    const float* ln_pair_w = (const float*)d_in[5];
    const float* ln_pair_b = (const float*)d_in[6];
    const float* w_b       = (const float*)d_in[7];
    const float* w_g       = (const float*)d_in[8];
    const float* w_out     = (const float*)d_in[9];
    const float* b_out     = (const float*)d_in[10];
    float* out = (float*)d_out;

    float* ws = (float*)d_ws;
    const size_t CH = 524288;     // 2048*256 floats
    float* q_t  = ws + 0 * CH;
    float* k_t  = ws + 1 * CH;
    float* v_t  = ws + 2 * CH;
    float* g_t  = ws + 3 * CH;
    float* b2   = ws + 4 * CH;
    float* ao   = ws + 5 * CH;
    float* Abuf = ws + 6 * CH;    // 1552 floats
    float* part = ws + 7 * CH;    // 4 x CH
    unsigned short* xhi  = (unsigned short*)(ws + 11 * CH);   // 2048*256 u16
    unsigned short* xlo  = xhi + M_ROWS * 256;
    unsigned short* whiT = (unsigned short*)(ws + 12 * CH);   // 1024*256 u16
    unsigned short* wloT = whiT + XW_N * 256;

    wconv_kernel<<<128, 256, 0, stream>>>(w_qkv, w_g, whiT, wloT);

    ln_msa_kernel<<<M_ROWS, 256, 0, stream>>>(msa_rep, ln_w, ln_b, xhi, xlo);

    xw_mfma_kernel<<<dim3(8, 32), 256, 0, stream>>>(
        xhi, xlo, whiT, wloT, q_t, k_t, v_t, g_t);

    pb_setup_kernel<<<1, 128, 0, stream>>>(ln_pair_w, ln_pair_b, w_b, Abuf);

    pair_bias_kernel<<<65536 / 64, 256, 0, stream>>>(pair_rep, Abuf, b2);

    attn_kernel<<<512, 256, 0, stream>>>(q_t, k_t, v_t, g_t, b2, ao);

    out_gemm_kernel<<<dim3(2, 32, 4), 256, 0, stream>>>(ao, w_out, part);

    reduce_out_kernel<<<512, 256, 0, stream>>>(part, b_out, out);
}

// Round 8
// 147.650 us; speedup vs baseline: 1.2941x; 1.0480x over previous
//
#include <hip/hip_runtime.h>
#include <math.h>

#define S_DIM 8
#define N_RES 256
#define MSA_DIM 256
#define PAIR_DIM 128
#define D_DIM 32
#define H_DIM 8
#define M_ROWS (S_DIM * N_RES)      // 2048
#define QKV_N (3 * H_DIM * D_DIM)   // 768
#define HD (H_DIM * D_DIM)          // 256
#define XW_N 1024                   // qkv(768) + gate(256)
#define LOG2E 1.4426950408889634f

typedef __attribute__((ext_vector_type(8))) short short8;
typedef __attribute__((ext_vector_type(4))) float floatx4;

// ---- wave64 sum via DPP; total lands in lane 63
#define DPP_ADD(x, ctrl, rmask)                                                \
    x += __int_as_float(__builtin_amdgcn_update_dpp(                           \
        0, __float_as_int(x), (ctrl), (rmask), 0xf, true))

__device__ __forceinline__ float wave_sum63(float x) {
    DPP_ADD(x, 0x111, 0xf);
    DPP_ADD(x, 0x112, 0xf);
    DPP_ADD(x, 0x114, 0xf);
    DPP_ADD(x, 0x118, 0xf);
    DPP_ADD(x, 0x142, 0xa);
    DPP_ADD(x, 0x143, 0xc);
    return x;
}

__device__ __forceinline__ float quad_sum(float x) {
    x += __int_as_float(__builtin_amdgcn_update_dpp(
        0, __float_as_int(x), 0xB1, 0xf, 0xf, true));
    x += __int_as_float(__builtin_amdgcn_update_dpp(
        0, __float_as_int(x), 0x4E, 0xf, 0xf, true));
    return x;
}

__device__ __forceinline__ unsigned short bf16rn(float v) {
    unsigned u = __float_as_uint(v);
    return (unsigned short)((u + 0x7FFF + ((u >> 16) & 1)) >> 16);
}

// =========== Kernel 1 "prep": pair_bias + wconv(W, w_out) + ln =============
// blocks [0,1024):    pair_bias, 64 rows/block
// blocks [1024,1152): split+transpose w_qkv|w_g -> whiT/wloT [1024 n][256 k]
// blocks [1152,1184): split+transpose+perm w_out -> wouthiT/woutloT [256][256]
// blocks [1184,3232): LayerNorm msa -> xhi/xlo bf16
__global__ __launch_bounds__(256) void prep_kernel(
    const float* __restrict__ pair, const float* __restrict__ lw,
    const float* __restrict__ lb, const float* __restrict__ wb,
    float* __restrict__ b2,
    const float* __restrict__ w_qkv, const float* __restrict__ w_g,
    unsigned short* __restrict__ whiT, unsigned short* __restrict__ wloT,
    const float* __restrict__ w_out,
    unsigned short* __restrict__ wouthiT, unsigned short* __restrict__ woutloT,
    const float* __restrict__ msa, const float* __restrict__ lnw,
    const float* __restrict__ lnb, unsigned short* __restrict__ xhi,
    unsigned short* __restrict__ xlo)
{
    __shared__ __align__(16) float shm[2080];  // As[1552] | Spart[264] | Qpart[264]
    int bx = blockIdx.x;
    int t = threadIdx.x;

    if (bx < 1024) {
        // ---------------- pair_bias ----------------
        float* As = shm;
        float* Spart = shm + 1552;
        float* Qpart = shm + 1816;
        if (t < 128) {
            float lwc = lw[t];
#pragma unroll
            for (int h = 0; h < 8; h++)
                As[t * 12 + h] = lwc * wb[t * 8 + h] * LOG2E;
        }
        __syncthreads();
        {
            int h = t >> 5, seg = t & 31, cbase = seg * 4;
            float sa = 0, sq = 0;
#pragma unroll
            for (int cc = 0; cc < 4; cc++) {
                int c = cbase + cc;
                sa += As[c * 12 + h];
                sq += lb[c] * wb[c * 8 + h];
            }
            Spart[h * 33 + seg] = sa;
            Qpart[h * 33 + seg] = sq * LOG2E;
        }
        __syncthreads();
        if (t < 8) {
            float s = 0, q = 0;
#pragma unroll
            for (int j = 0; j < 32; j++) {
                s += Spart[t * 33 + j];
                q += Qpart[t * 33 + j];
            }
            As[1536 + t] = s;
            As[1544 + t] = q;
        }
        __syncthreads();
        int row = bx * 64 + (t >> 2);
        int q = t & 3;
        const float* in = pair + (size_t)row * PAIR_DIM;
        float4 x4[8];
#pragma unroll
        for (int it = 0; it < 8; it++)
            x4[it] = *(const float4*)&in[it * 16 + q * 4];
        float s = 0, s2 = 0;
        float dot[8] = {};
#pragma unroll
        for (int it = 0; it < 8; it++) {
            float xk[4];
            *(float4*)xk = x4[it];
#pragma unroll
            for (int k = 0; k < 4; k++) {
                int c = it * 16 + q * 4 + k;
                float xv = xk[k];
                s += xv; s2 += xv * xv;
                float4 A0 = *(const float4*)&As[c * 12];
                float4 A1 = *(const float4*)&As[c * 12 + 4];
                dot[0] += xv * A0.x; dot[1] += xv * A0.y;
                dot[2] += xv * A0.z; dot[3] += xv * A0.w;
                dot[4] += xv * A1.x; dot[5] += xv * A1.y;
                dot[6] += xv * A1.z; dot[7] += xv * A1.w;
            }
        }
        s = quad_sum(s);
        s2 = quad_sum(s2);
#pragma unroll
        for (int h = 0; h < 8; h++) dot[h] = quad_sum(dot[h]);
        float mu = s * (1.0f / 128.0f);
        float var = s2 * (1.0f / 128.0f) - mu * mu;
        float rs = rsqrtf(var + 1e-5f);
        int h0 = q * 2;
#pragma unroll
        for (int u = 0; u < 2; u++) {
            int h = h0 + u;
            b2[h * 65536 + row] = rs * (dot[h] - mu * As[1536 + h]) + As[1544 + h];
        }
    } else if (bx < 1152) {
        // ---------------- wconv for W = [w_qkv | w_g] ----------------
        int id = (bx - 1024) * 256 + t;       // 32768
        int n = id >> 5, oct = id & 31, k0 = oct * 8;
        const float* src;
        int stride;
        if (n < QKV_N) { src = w_qkv + n; stride = QKV_N; }
        else           { src = w_g + (n - QKV_N); stride = HD; }
        unsigned short h8[8], l8[8];
#pragma unroll
        for (int j = 0; j < 8; j++) {
            float v = src[(size_t)(k0 + j) * stride];
            unsigned short h = bf16rn(v);
            h8[j] = h;
            l8[j] = bf16rn(v - __uint_as_float((unsigned)h << 16));
        }
        *(short8*)&whiT[n * 256 + k0] = *(short8*)h8;
        *(short8*)&wloT[n * 256 + k0] = *(short8*)l8;
    } else if (bx < 1184) {
        // ------- wconv for w_out (ao-layout row perm) -------
        int id = (bx - 1152) * 256 + t;       // 8192
        int n = id >> 5, oct = id & 31, k0 = oct * 8;
        unsigned short h8[8], l8[8];
#pragma unroll
        for (int j = 0; j < 8; j++) {
            int k = k0 + j;
            int wrow = (k & 31) * 8 + (k >> 5);
            float v = w_out[(size_t)wrow * 256 + n];
            unsigned short h = bf16rn(v);
            h8[j] = h;
            l8[j] = bf16rn(v - __uint_as_float((unsigned)h << 16));
        }
        *(short8*)&wouthiT[n * 256 + k0] = *(short8*)h8;
        *(short8*)&woutloT[n * 256 + k0] = *(short8*)l8;
    } else {
        // ---------------- LayerNorm of msa ----------------
        int row = bx - 1184;
        float v = msa[row * MSA_DIM + t];
        float s1 = wave_sum63(v);
        float s2 = wave_sum63(v * v);
        float* r1 = shm;
        float* r2 = shm + 4;
        int wave = t >> 6, lane = t & 63;
        if (lane == 63) { r1[wave] = s1; r2[wave] = s2; }
        __syncthreads();
        float S1 = r1[0] + r1[1] + r1[2] + r1[3];
        float S2 = r2[0] + r2[1] + r2[2] + r2[3];
        float mu = S1 * (1.0f / 256.0f);
        float var = S2 * (1.0f / 256.0f) - mu * mu;
        float rs = rsqrtf(var + 1e-5f);
        float y = (v - mu) * rs * lnw[t] + lnb[t];
        unsigned short h = bf16rn(y);
        xhi[row * 256 + t] = h;
        xlo[row * 256 + t] = bf16rn(y - __uint_as_float((unsigned)h << 16));
    }
}

// ------- Kernel 2: xw GEMM via bf16x3 MFMA (verified R7 structure) ---------
__global__ __launch_bounds__(256) void xw_mfma_kernel(
    const unsigned short* __restrict__ xhi, const unsigned short* __restrict__ xlo,
    const unsigned short* __restrict__ whiT, const unsigned short* __restrict__ wloT,
    float* __restrict__ q_t, float* __restrict__ k_t,
    float* __restrict__ v_t, float* __restrict__ g_t)
{
    __shared__ unsigned short As[64 * 72];
    __shared__ unsigned short Bs[128 * 72];
    __shared__ float Cs[64 * 132];
    int t = threadIdx.x;
    int n0 = blockIdx.x * 128, m0 = blockIdx.y * 64;
    int w = t >> 6, L = t & 63;
    int wm = (w & 1) * 32, wn = (w >> 1) * 64;
    int l15 = L & 15, l4 = L >> 4;
    int alm = t >> 3, alk = (t & 7) * 8;
    floatx4 acc[2][4];
#pragma unroll
    for (int a = 0; a < 2; a++)
#pragma unroll
        for (int b = 0; b < 4; b++) acc[a][b] = (floatx4){0, 0, 0, 0};

    short8 pa0 = *(const short8*)&xhi[(m0 + alm) * 256 + alk];
    short8 pa1 = *(const short8*)&xhi[(m0 + alm + 32) * 256 + alk];
    short8 pb[4];
#pragma unroll
    for (int j = 0; j < 4; j++) {
        int id = t + 256 * j;
        int bn = id >> 3, bc = (id & 7) * 8;
        pb[j] = *(const short8*)&whiT[(n0 + bn) * 256 + bc];
    }

    for (int r = 0; r < 12; r++) {
        __syncthreads();
        *(short8*)&As[alm * 72 + alk] = pa0;
        *(short8*)&As[(alm + 32) * 72 + alk] = pa1;
#pragma unroll
        for (int j = 0; j < 4; j++) {
            int id = t + 256 * j;
            int bn = id >> 3, bc = (id & 7) * 8;
            *(short8*)&Bs[bn * 72 + bc] = pb[j];
        }
        __syncthreads();
        if (r < 11) {
            int rn = r + 1;
            int seg = rn >> 2, kb = (rn & 3) * 64;
            const unsigned short* An = (seg == 1) ? xlo : xhi;
            const unsigned short* Bn = (seg == 2) ? wloT : whiT;
            pa0 = *(const short8*)&An[(m0 + alm) * 256 + kb + alk];
            pa1 = *(const short8*)&An[(m0 + alm + 32) * 256 + kb + alk];
#pragma unroll
            for (int j = 0; j < 4; j++) {
                int id = t + 256 * j;
                int bn = id >> 3, bc = (id & 7) * 8;
                pb[j] = *(const short8*)&Bn[(n0 + bn) * 256 + kb + bc];
            }
        }
#pragma unroll
        for (int ks = 0; ks < 2; ks++) {
            int ko = ks * 32 + l4 * 8;
            short8 af[2], bf[4];
#pragma unroll
            for (int a = 0; a < 2; a++)
                af[a] = *(short8*)&As[(wm + a * 16 + l15) * 72 + ko];
#pragma unroll
            for (int b = 0; b < 4; b++)
                bf[b] = *(short8*)&Bs[(wn + b * 16 + l15) * 72 + ko];
#pragma unroll
            for (int a = 0; a < 2; a++)
#pragma unroll
                for (int b = 0; b < 4; b++)
                    acc[a][b] = __builtin_amdgcn_mfma_f32_16x16x32_bf16(
                        af[a], bf[b], acc[a][b], 0, 0, 0);
        }
    }
#pragma unroll
    for (int a = 0; a < 2; a++)
#pragma unroll
        for (int b = 0; b < 4; b++) {
            int nl = wn + b * 16 + l15;
#pragma unroll
            for (int rg = 0; rg < 4; rg++) {
                int ml = wm + a * 16 + l4 * 4 + rg;
                Cs[ml * 132 + nl] = acc[a][b][rg];
            }
        }
    __syncthreads();
    int qkv_mode = (n0 < QKV_N);
    int chunk = n0 >> 8;
    int dbase = (n0 & 255) >> 3;
#pragma unroll
    for (int j = 0; j < 8; j++) {
        int id = t + 256 * j;
        int m = id >> 5;
        int h = (id >> 2) & 7;
        int dq = id & 3;
        float vals[4];
#pragma unroll
        for (int jj = 0; jj < 4; jj++)
            vals[jj] = Cs[m * 132 + (dq * 4 + jj) * 8 + h];
        int mm = m0 + m;
        int daddr = dbase + dq * 4;
        if (qkv_mode) {
            float* dst = (chunk == 0) ? q_t : ((chunk == 1) ? k_t : v_t);
            *(float4*)&dst[(size_t)(h * M_ROWS + mm) * D_DIM + daddr] =
                *(float4*)vals;
        } else {
            float4 o;
            o.x = 1.0f / (1.0f + __expf(-vals[0]));
            o.y = 1.0f / (1.0f + __expf(-vals[1]));
            o.z = 1.0f / (1.0f + __expf(-vals[2]));
            o.w = 1.0f / (1.0f + __expf(-vals[3]));
            *(float4*)&g_t[(size_t)(h * M_ROWS + mm) * D_DIM + daddr] = o;
        }
    }
}

// ---------------- Kernel 3: attention; emits ao as bf16 hi/lo --------------
__global__ __launch_bounds__(256) void attn_kernel(
    const float* __restrict__ q_t, const float* __restrict__ k_t,
    const float* __restrict__ v_t, const float* __restrict__ g_t,
    const float* __restrict__ b2, unsigned short* __restrict__ ao_hi,
    unsigned short* __restrict__ ao_lo)
{
    __shared__ float k_sh[256][32];
    __shared__ float v_sh[256][32];
    int blk = blockIdx.x;
    int s = blk >> 6, h = (blk >> 3) & 7, it = blk & 7;
    int t = threadIdx.x;
    const float* kb = k_t + (size_t)(h * M_ROWS + s * N_RES) * D_DIM;
    const float* vb = v_t + (size_t)(h * M_ROWS + s * N_RES) * D_DIM;
    for (int idx = t; idx < 2048; idx += 256) {
        ((float4*)k_sh)[idx] = ((const float4*)kb)[idx];
        ((float4*)v_sh)[idx] = ((const float4*)vb)[idx];
    }
    __syncthreads();
    int jp = t & 3, dg = (t >> 2) & 7, li = t >> 5;
    int d0 = dg * 4;
    const float SCL2 = 0.17677669529663687f * LOG2E;
    int ig[4], mrow[4];
    float qs[4][4];
#pragma unroll
    for (int r = 0; r < 4; r++) {
        ig[r] = it * 32 + r * 8 + li;
        mrow[r] = s * N_RES + ig[r];
        float4 q4 = *(const float4*)&q_t[(size_t)(h * M_ROWS + mrow[r]) * D_DIM + d0];
        qs[r][0] = q4.x * SCL2; qs[r][1] = q4.y * SCL2;
        qs[r][2] = q4.z * SCL2; qs[r][3] = q4.w * SCL2;
    }
    float den[4][4] = {}, acc[4][4] = {};
    const float* bbase = b2 + h * 65536;
    for (int js4 = 0; js4 < 16; js4++) {
        float bb[4][4];
#pragma unroll
        for (int r = 0; r < 4; r++)
            *(float4*)&bb[r][0] =
                *(const float4*)&bbase[ig[r] * 256 + jp * 64 + js4 * 4];
#pragma unroll
        for (int u = 0; u < 4; u++) {
            int j = jp * 64 + js4 * 4 + u;
            float ka[4], va[4];
            *(float4*)ka = *(const float4*)&k_sh[j][d0];
            *(float4*)va = *(const float4*)&v_sh[j][d0];
#pragma unroll
            for (int r = 0; r < 4; r++) {
#pragma unroll
                for (int c = 0; c < 4; c++) {
                    float e = __builtin_amdgcn_exp2f(qs[r][c] * ka[c] + bb[r][u]);
                    den[r][c] += e;
                    acc[r][c] += e * va[c];
                }
            }
        }
    }
#pragma unroll
    for (int r = 0; r < 4; r++)
#pragma unroll
        for (int c = 0; c < 4; c++) {
            den[r][c] = quad_sum(den[r][c]);
            acc[r][c] = quad_sum(acc[r][c]);
        }
    if (jp == 0) {
#pragma unroll
        for (int r = 0; r < 4; r++) {
            float4 g4 = *(const float4*)&g_t[(size_t)(h * M_ROWS + mrow[r]) * D_DIM + d0];
            float o[4];
            o[0] = g4.x * acc[r][0] / den[r][0];
            o[1] = g4.y * acc[r][1] / den[r][1];
            o[2] = g4.z * acc[r][2] / den[r][2];
            o[3] = g4.w * acc[r][3] / den[r][3];
            unsigned short hi[4], lo[4];
#pragma unroll
            for (int c = 0; c < 4; c++) {
                hi[c] = bf16rn(o[c]);
                lo[c] = bf16rn(o[c] - __uint_as_float((unsigned)hi[c] << 16));
            }
            size_t base = (size_t)mrow[r] * 256 + h * 32 + d0;
            uint2 ph, pl;
            ph.x = (unsigned)hi[0] | ((unsigned)hi[1] << 16);
            ph.y = (unsigned)hi[2] | ((unsigned)hi[3] << 16);
            pl.x = (unsigned)lo[0] | ((unsigned)lo[1] << 16);
            pl.y = (unsigned)lo[2] | ((unsigned)lo[3] << 16);
            *(uint2*)&ao_hi[base] = ph;
            *(uint2*)&ao_lo[base] = pl;
        }
    }
}

// ------- Kernel 4: out projection via bf16x3 MFMA + bias -------------------
// out[m][n] = sum_k ao[m][k'] * woutT[n][k'] + b_out[n];  grid (2, 32)
__global__ __launch_bounds__(256) void out_mfma_kernel(
    const unsigned short* __restrict__ ahi, const unsigned short* __restrict__ alo,
    const unsigned short* __restrict__ whi, const unsigned short* __restrict__ wlo,
    const float* __restrict__ bias, float* __restrict__ out)
{
    __shared__ unsigned short As[64 * 72];
    __shared__ unsigned short Bs[128 * 72];
    __shared__ float Cs[64 * 132];
    int t = threadIdx.x;
    int n0 = blockIdx.x * 128, m0 = blockIdx.y * 64;
    int w = t >> 6, L = t & 63;
    int wm = (w & 1) * 32, wn = (w >> 1) * 64;
    int l15 = L & 15, l4 = L >> 4;
    int alm = t >> 3, alk = (t & 7) * 8;
    floatx4 acc[2][4];
#pragma unroll
    for (int a = 0; a < 2; a++)
#pragma unroll
        for (int b = 0; b < 4; b++) acc[a][b] = (floatx4){0, 0, 0, 0};

    short8 pa0 = *(const short8*)&ahi[(m0 + alm) * 256 + alk];
    short8 pa1 = *(const short8*)&ahi[(m0 + alm + 32) * 256 + alk];
    short8 pb[4];
#pragma unroll
    for (int j = 0; j < 4; j++) {
        int id = t + 256 * j;
        int bn = id >> 3, bc = (id & 7) * 8;
        pb[j] = *(const short8*)&whi[(n0 + bn) * 256 + bc];
    }

    for (int r = 0; r < 12; r++) {
        __syncthreads();
        *(short8*)&As[alm * 72 + alk] = pa0;
        *(short8*)&As[(alm + 32) * 72 + alk] = pa1;
#pragma unroll
        for (int j = 0; j < 4; j++) {
            int id = t + 256 * j;
            int bn = id >> 3, bc = (id & 7) * 8;
            *(short8*)&Bs[bn * 72 + bc] = pb[j];
        }
        __syncthreads();
        if (r < 11) {
            int rn = r + 1;
            int seg = rn >> 2, kb = (rn & 3) * 64;
            const unsigned short* An = (seg == 1) ? alo : ahi;
            const unsigned short* Bn = (seg == 2) ? wlo : whi;
            pa0 = *(const short8*)&An[(m0 + alm) * 256 + kb + alk];
            pa1 = *(const short8*)&An[(m0 + alm + 32) * 256 + kb + alk];
#pragma unroll
            for (int j = 0; j < 4; j++) {
                int id = t + 256 * j;
                int bn = id >> 3, bc = (id & 7) * 8;
                pb[j] = *(const short8*)&Bn[(n0 + bn) * 256 + kb + bc];
            }
        }
#pragma unroll
        for (int ks = 0; ks < 2; ks++) {
            int ko = ks * 32 + l4 * 8;
            short8 af[2], bf[4];
#pragma unroll
            for (int a = 0; a < 2; a++)
                af[a] = *(short8*)&As[(wm + a * 16 + l15) * 72 + ko];
#pragma unroll
            for (int b = 0; b < 4; b++)
                bf[b] = *(short8*)&Bs[(wn + b * 16 + l15) * 72 + ko];
#pragma unroll
            for (int a = 0; a < 2; a++)
#pragma unroll
                for (int b = 0; b < 4; b++)
                    acc[a][b] = __builtin_amdgcn_mfma_f32_16x16x32_bf16(
                        af[a], bf[b], acc[a][b], 0, 0, 0);
        }
    }
#pragma unroll
    for (int a = 0; a < 2; a++)
#pragma unroll
        for (int b = 0; b < 4; b++) {
            int nl = wn + b * 16 + l15;
#pragma unroll
            for (int rg = 0; rg < 4; rg++) {
                int ml = wm + a * 16 + l4 * 4 + rg;
                Cs[ml * 132 + nl] = acc[a][b][rg];
            }
        }
    __syncthreads();
#pragma unroll
    for (int j = 0; j < 8; j++) {
        int id = t + 256 * j;
        int m = id >> 5, nc = (id & 31) * 4;
        float4 v = *(float4*)&Cs[m * 132 + nc];
        float4 bb = *(const float4*)&bias[n0 + nc];
        float4 o;
        o.x = v.x + bb.x; o.y = v.y + bb.y;
        o.z = v.z + bb.z; o.w = v.w + bb.w;
        *(float4*)&out[(size_t)(m0 + m) * 256 + n0 + nc] = o;
    }
}

extern "C" void kernel_launch(void* const* d_in, const int* in_sizes, int n_in,
                              void* d_out, int out_size, void* d_ws, size_t ws_size,
                              hipStream_t stream)
{
    const float* msa_rep   = (const float*)d_in[0];
    const float* pair_rep  = (const float*)d_in[1];
    const float* ln_w      = (const float*)d_in[2];
    const float* ln_b      = (const float*)d_in[3];
    const float* w_qkv     = (const float*)d_in[4];
    const float* ln_pair_w = (const float*)d_in[5];
    const float* ln_pair_b = (const float*)d_in[6];
    const float* w_b       = (const float*)d_in[7];
    const float* w_g       = (const float*)d_in[8];
    const float* w_out     = (const float*)d_in[9];
    const float* b_out     = (const float*)d_in[10];
    float* out = (float*)d_out;

    float* ws = (float*)d_ws;
    const size_t CH = 524288;     // 2048*256 floats
    float* q_t = ws + 0 * CH;
    float* k_t = ws + 1 * CH;
    float* v_t = ws + 2 * CH;
    float* g_t = ws + 3 * CH;
    float* b2  = ws + 4 * CH;
    unsigned short* ao_hi   = (unsigned short*)(ws + 5 * CH);
    unsigned short* ao_lo   = ao_hi + (size_t)M_ROWS * 256;
    unsigned short* xhi     = (unsigned short*)(ws + 6 * CH);
    unsigned short* xlo     = xhi + (size_t)M_ROWS * 256;
    unsigned short* whiT    = (unsigned short*)(ws + 7 * CH);
    unsigned short* wloT    = whiT + (size_t)XW_N * 256;
    unsigned short* wouthiT = (unsigned short*)(ws + 8 * CH);
    unsigned short* woutloT = wouthiT + 65536;

    prep_kernel<<<3232, 256, 0, stream>>>(
        pair_rep, ln_pair_w, ln_pair_b, w_b, b2,
        w_qkv, w_g, whiT, wloT,
        w_out, wouthiT, woutloT,
        msa_rep, ln_w, ln_b, xhi, xlo);

    xw_mfma_kernel<<<dim3(8, 32), 256, 0, stream>>>(
        xhi, xlo, whiT, wloT, q_t, k_t, v_t, g_t);

    attn_kernel<<<512, 256, 0, stream>>>(q_t, k_t, v_t, g_t, b2, ao_hi, ao_lo);

    out_mfma_kernel<<<dim3(2, 32), 256, 0, stream>>>(
        ao_hi, ao_lo, wouthiT, woutloT, b_out, out);
}

// Round 9
// 145.794 us; speedup vs baseline: 1.3105x; 1.0127x over previous
//
#include <hip/hip_runtime.h>
#include <math.h>

#define S_DIM 8
#define N_RES 256
#define MSA_DIM 256
#define PAIR_DIM 128
#define D_DIM 32
#define H_DIM 8
#define M_ROWS (S_DIM * N_RES)      // 2048
#define QKV_N (3 * H_DIM * D_DIM)   // 768
#define HD (H_DIM * D_DIM)          // 256
#define XW_N 1024                   // qkv(768) + gate(256)
#define LOG2E 1.4426950408889634f

typedef __attribute__((ext_vector_type(8))) short short8;
typedef __attribute__((ext_vector_type(4))) float floatx4;

// ---- wave64 sum via DPP; total lands in lane 63
#define DPP_ADD(x, ctrl, rmask)                                                \
    x += __int_as_float(__builtin_amdgcn_update_dpp(                           \
        0, __float_as_int(x), (ctrl), (rmask), 0xf, true))

__device__ __forceinline__ float wave_sum63(float x) {
    DPP_ADD(x, 0x111, 0xf);
    DPP_ADD(x, 0x112, 0xf);
    DPP_ADD(x, 0x114, 0xf);
    DPP_ADD(x, 0x118, 0xf);
    DPP_ADD(x, 0x142, 0xa);
    DPP_ADD(x, 0x143, 0xc);
    return x;
}

__device__ __forceinline__ float quad_sum(float x) {
    x += __int_as_float(__builtin_amdgcn_update_dpp(
        0, __float_as_int(x), 0xB1, 0xf, 0xf, true));
    x += __int_as_float(__builtin_amdgcn_update_dpp(
        0, __float_as_int(x), 0x4E, 0xf, 0xf, true));
    return x;
}

__device__ __forceinline__ unsigned short bf16rn(float v) {
    unsigned u = __float_as_uint(v);
    return (unsigned short)((u + 0x7FFF + ((u >> 16) & 1)) >> 16);
}

// =========== Kernel 1 "prep": pair_bias + wconv(W, w_out) + ln =============
// blocks [0,1024):    pair_bias, 64 rows/block
// blocks [1024,1152): split+transpose w_qkv|w_g -> whiT/wloT [1024 n][256 k]
// blocks [1152,1184): split+transpose+perm w_out -> wouthiT/woutloT [256][256]
// blocks [1184,3232): LayerNorm msa -> xhi/xlo bf16
__global__ __launch_bounds__(256) void prep_kernel(
    const float* __restrict__ pair, const float* __restrict__ lw,
    const float* __restrict__ lb, const float* __restrict__ wb,
    float* __restrict__ b2,
    const float* __restrict__ w_qkv, const float* __restrict__ w_g,
    unsigned short* __restrict__ whiT, unsigned short* __restrict__ wloT,
    const float* __restrict__ w_out,
    unsigned short* __restrict__ wouthiT, unsigned short* __restrict__ woutloT,
    const float* __restrict__ msa, const float* __restrict__ lnw,
    const float* __restrict__ lnb, unsigned short* __restrict__ xhi,
    unsigned short* __restrict__ xlo)
{
    __shared__ __align__(16) float shm[2080];  // As[1552] | Spart[264] | Qpart[264]
    int bx = blockIdx.x;
    int t = threadIdx.x;

    if (bx < 1024) {
        // ---------------- pair_bias ----------------
        float* As = shm;
        float* Spart = shm + 1552;
        float* Qpart = shm + 1816;
        if (t < 128) {
            float lwc = lw[t];
#pragma unroll
            for (int h = 0; h < 8; h++)
                As[t * 12 + h] = lwc * wb[t * 8 + h] * LOG2E;
        }
        __syncthreads();
        {
            int h = t >> 5, seg = t & 31, cbase = seg * 4;
            float sa = 0, sq = 0;
#pragma unroll
            for (int cc = 0; cc < 4; cc++) {
                int c = cbase + cc;
                sa += As[c * 12 + h];
                sq += lb[c] * wb[c * 8 + h];
            }
            Spart[h * 33 + seg] = sa;
            Qpart[h * 33 + seg] = sq * LOG2E;
        }
        __syncthreads();
        if (t < 8) {
            float s = 0, q = 0;
#pragma unroll
            for (int j = 0; j < 32; j++) {
                s += Spart[t * 33 + j];
                q += Qpart[t * 33 + j];
            }
            As[1536 + t] = s;
            As[1544 + t] = q;
        }
        __syncthreads();
        int row = bx * 64 + (t >> 2);
        int q = t & 3;
        const float* in = pair + (size_t)row * PAIR_DIM;
        float4 x4[8];
#pragma unroll
        for (int it = 0; it < 8; it++)
            x4[it] = *(const float4*)&in[it * 16 + q * 4];
        float s = 0, s2 = 0;
        float dot[8] = {};
#pragma unroll
        for (int it = 0; it < 8; it++) {
            float xk[4];
            *(float4*)xk = x4[it];
#pragma unroll
            for (int k = 0; k < 4; k++) {
                int c = it * 16 + q * 4 + k;
                float xv = xk[k];
                s += xv; s2 += xv * xv;
                float4 A0 = *(const float4*)&As[c * 12];
                float4 A1 = *(const float4*)&As[c * 12 + 4];
                dot[0] += xv * A0.x; dot[1] += xv * A0.y;
                dot[2] += xv * A0.z; dot[3] += xv * A0.w;
                dot[4] += xv * A1.x; dot[5] += xv * A1.y;
                dot[6] += xv * A1.z; dot[7] += xv * A1.w;
            }
        }
        s = quad_sum(s);
        s2 = quad_sum(s2);
#pragma unroll
        for (int h = 0; h < 8; h++) dot[h] = quad_sum(dot[h]);
        float mu = s * (1.0f / 128.0f);
        float var = s2 * (1.0f / 128.0f) - mu * mu;
        float rs = rsqrtf(var + 1e-5f);
        int h0 = q * 2;
#pragma unroll
        for (int u = 0; u < 2; u++) {
            int h = h0 + u;
            b2[h * 65536 + row] = rs * (dot[h] - mu * As[1536 + h]) + As[1544 + h];
        }
    } else if (bx < 1152) {
        // ---------------- wconv for W = [w_qkv | w_g] ----------------
        int id = (bx - 1024) * 256 + t;       // 32768
        int n = id >> 5, oct = id & 31, k0 = oct * 8;
        const float* src;
        int stride;
        if (n < QKV_N) { src = w_qkv + n; stride = QKV_N; }
        else           { src = w_g + (n - QKV_N); stride = HD; }
        unsigned short h8[8], l8[8];
#pragma unroll
        for (int j = 0; j < 8; j++) {
            float v = src[(size_t)(k0 + j) * stride];
            unsigned short h = bf16rn(v);
            h8[j] = h;
            l8[j] = bf16rn(v - __uint_as_float((unsigned)h << 16));
        }
        *(short8*)&whiT[n * 256 + k0] = *(short8*)h8;
        *(short8*)&wloT[n * 256 + k0] = *(short8*)l8;
    } else if (bx < 1184) {
        // ------- wconv for w_out (ao-layout row perm) -------
        int id = (bx - 1152) * 256 + t;       // 8192
        int n = id >> 5, oct = id & 31, k0 = oct * 8;
        unsigned short h8[8], l8[8];
#pragma unroll
        for (int j = 0; j < 8; j++) {
            int k = k0 + j;
            int wrow = (k & 31) * 8 + (k >> 5);
            float v = w_out[(size_t)wrow * 256 + n];
            unsigned short h = bf16rn(v);
            h8[j] = h;
            l8[j] = bf16rn(v - __uint_as_float((unsigned)h << 16));
        }
        *(short8*)&wouthiT[n * 256 + k0] = *(short8*)h8;
        *(short8*)&woutloT[n * 256 + k0] = *(short8*)l8;
    } else {
        // ---------------- LayerNorm of msa ----------------
        int row = bx - 1184;
        float v = msa[row * MSA_DIM + t];
        float s1 = wave_sum63(v);
        float s2 = wave_sum63(v * v);
        float* r1 = shm;
        float* r2 = shm + 4;
        int wave = t >> 6, lane = t & 63;
        if (lane == 63) { r1[wave] = s1; r2[wave] = s2; }
        __syncthreads();
        float S1 = r1[0] + r1[1] + r1[2] + r1[3];
        float S2 = r2[0] + r2[1] + r2[2] + r2[3];
        float mu = S1 * (1.0f / 256.0f);
        float var = S2 * (1.0f / 256.0f) - mu * mu;
        float rs = rsqrtf(var + 1e-5f);
        float y = (v - mu) * rs * lnw[t] + lnb[t];
        unsigned short h = bf16rn(y);
        xhi[row * 256 + t] = h;
        xlo[row * 256 + t] = bf16rn(y - __uint_as_float((unsigned)h << 16));
    }
}

// ------- Kernel 2: xw GEMM via bf16x3 MFMA (verified R7 structure) ---------
__global__ __launch_bounds__(256) void xw_mfma_kernel(
    const unsigned short* __restrict__ xhi, const unsigned short* __restrict__ xlo,
    const unsigned short* __restrict__ whiT, const unsigned short* __restrict__ wloT,
    float* __restrict__ q_t, float* __restrict__ k_t,
    float* __restrict__ v_t, float* __restrict__ g_t)
{
    __shared__ unsigned short As[64 * 72];
    __shared__ unsigned short Bs[128 * 72];
    __shared__ float Cs[64 * 132];
    int t = threadIdx.x;
    int n0 = blockIdx.x * 128, m0 = blockIdx.y * 64;
    int w = t >> 6, L = t & 63;
    int wm = (w & 1) * 32, wn = (w >> 1) * 64;
    int l15 = L & 15, l4 = L >> 4;
    int alm = t >> 3, alk = (t & 7) * 8;
    floatx4 acc[2][4];
#pragma unroll
    for (int a = 0; a < 2; a++)
#pragma unroll
        for (int b = 0; b < 4; b++) acc[a][b] = (floatx4){0, 0, 0, 0};

    short8 pa0 = *(const short8*)&xhi[(m0 + alm) * 256 + alk];
    short8 pa1 = *(const short8*)&xhi[(m0 + alm + 32) * 256 + alk];
    short8 pb[4];
#pragma unroll
    for (int j = 0; j < 4; j++) {
        int id = t + 256 * j;
        int bn = id >> 3, bc = (id & 7) * 8;
        pb[j] = *(const short8*)&whiT[(n0 + bn) * 256 + bc];
    }

    for (int r = 0; r < 12; r++) {
        __syncthreads();
        *(short8*)&As[alm * 72 + alk] = pa0;
        *(short8*)&As[(alm + 32) * 72 + alk] = pa1;
#pragma unroll
        for (int j = 0; j < 4; j++) {
            int id = t + 256 * j;
            int bn = id >> 3, bc = (id & 7) * 8;
            *(short8*)&Bs[bn * 72 + bc] = pb[j];
        }
        __syncthreads();
        if (r < 11) {
            int rn = r + 1;
            int seg = rn >> 2, kb = (rn & 3) * 64;
            const unsigned short* An = (seg == 1) ? xlo : xhi;
            const unsigned short* Bn = (seg == 2) ? wloT : whiT;
            pa0 = *(const short8*)&An[(m0 + alm) * 256 + kb + alk];
            pa1 = *(const short8*)&An[(m0 + alm + 32) * 256 + kb + alk];
#pragma unroll
            for (int j = 0; j < 4; j++) {
                int id = t + 256 * j;
                int bn = id >> 3, bc = (id & 7) * 8;
                pb[j] = *(const short8*)&Bn[(n0 + bn) * 256 + kb + bc];
            }
        }
#pragma unroll
        for (int ks = 0; ks < 2; ks++) {
            int ko = ks * 32 + l4 * 8;
            short8 af[2], bf[4];
#pragma unroll
            for (int a = 0; a < 2; a++)
                af[a] = *(short8*)&As[(wm + a * 16 + l15) * 72 + ko];
#pragma unroll
            for (int b = 0; b < 4; b++)
                bf[b] = *(short8*)&Bs[(wn + b * 16 + l15) * 72 + ko];
#pragma unroll
            for (int a = 0; a < 2; a++)
#pragma unroll
                for (int b = 0; b < 4; b++)
                    acc[a][b] = __builtin_amdgcn_mfma_f32_16x16x32_bf16(
                        af[a], bf[b], acc[a][b], 0, 0, 0);
        }
    }
#pragma unroll
    for (int a = 0; a < 2; a++)
#pragma unroll
        for (int b = 0; b < 4; b++) {
            int nl = wn + b * 16 + l15;
#pragma unroll
            for (int rg = 0; rg < 4; rg++) {
                int ml = wm + a * 16 + l4 * 4 + rg;
                Cs[ml * 132 + nl] = acc[a][b][rg];
            }
        }
    __syncthreads();
    int qkv_mode = (n0 < QKV_N);
    int chunk = n0 >> 8;
    int dbase = (n0 & 255) >> 3;
#pragma unroll
    for (int j = 0; j < 8; j++) {
        int id = t + 256 * j;
        int m = id >> 5;
        int h = (id >> 2) & 7;
        int dq = id & 3;
        float vals[4];
#pragma unroll
        for (int jj = 0; jj < 4; jj++)
            vals[jj] = Cs[m * 132 + (dq * 4 + jj) * 8 + h];
        int mm = m0 + m;
        int daddr = dbase + dq * 4;
        if (qkv_mode) {
            float* dst = (chunk == 0) ? q_t : ((chunk == 1) ? k_t : v_t);
            *(float4*)&dst[(size_t)(h * M_ROWS + mm) * D_DIM + daddr] =
                *(float4*)vals;
        } else {
            float4 o;
            o.x = 1.0f / (1.0f + __expf(-vals[0]));
            o.y = 1.0f / (1.0f + __expf(-vals[1]));
            o.z = 1.0f / (1.0f + __expf(-vals[2]));
            o.w = 1.0f / (1.0f + __expf(-vals[3]));
            *(float4*)&g_t[(size_t)(h * M_ROWS + mm) * D_DIM + daddr] = o;
        }
    }
}

// ---------------- Kernel 3: attention; emits ao as bf16 hi/lo --------------
// Block map: h = bx&7 (XCD-locality: all blocks of head h share an XCD via
// round-robin dispatch, so b2's 2MB head-slice stays L2-resident across the
// 8x s-reuse), s = (bx>>3)&7, it = bx>>6.
__global__ __launch_bounds__(256) void attn_kernel(
    const float* __restrict__ q_t, const float* __restrict__ k_t,
    const float* __restrict__ v_t, const float* __restrict__ g_t,
    const float* __restrict__ b2, unsigned short* __restrict__ ao_hi,
    unsigned short* __restrict__ ao_lo)
{
    __shared__ float k_sh[256][32];
    __shared__ float v_sh[256][32];
    int blk = blockIdx.x;
    int h = blk & 7, s = (blk >> 3) & 7, it = blk >> 6;
    int t = threadIdx.x;
    const float* kb = k_t + (size_t)(h * M_ROWS + s * N_RES) * D_DIM;
    const float* vb = v_t + (size_t)(h * M_ROWS + s * N_RES) * D_DIM;
    for (int idx = t; idx < 2048; idx += 256) {
        ((float4*)k_sh)[idx] = ((const float4*)kb)[idx];
        ((float4*)v_sh)[idx] = ((const float4*)vb)[idx];
    }
    __syncthreads();
    int jp = t & 3, dg = (t >> 2) & 7, li = t >> 5;
    int d0 = dg * 4;
    const float SCL2 = 0.17677669529663687f * LOG2E;
    int ig[4], mrow[4];
    float qs[4][4];
#pragma unroll
    for (int r = 0; r < 4; r++) {
        ig[r] = it * 32 + r * 8 + li;
        mrow[r] = s * N_RES + ig[r];
        float4 q4 = *(const float4*)&q_t[(size_t)(h * M_ROWS + mrow[r]) * D_DIM + d0];
        qs[r][0] = q4.x * SCL2; qs[r][1] = q4.y * SCL2;
        qs[r][2] = q4.z * SCL2; qs[r][3] = q4.w * SCL2;
    }
    float den[4][4] = {}, acc[4][4] = {};
    const float* bbase = b2 + h * 65536;
    for (int js4 = 0; js4 < 16; js4++) {
        float bb[4][4];
#pragma unroll
        for (int r = 0; r < 4; r++)
            *(float4*)&bb[r][0] =
                *(const float4*)&bbase[ig[r] * 256 + jp * 64 + js4 * 4];
#pragma unroll
        for (int u = 0; u < 4; u++) {
            int j = jp * 64 + js4 * 4 + u;
            float ka[4], va[4];
            *(float4*)ka = *(const float4*)&k_sh[j][d0];
            *(float4*)va = *(const float4*)&v_sh[j][d0];
#pragma unroll
            for (int r = 0; r < 4; r++) {
#pragma unroll
                for (int c = 0; c < 4; c++) {
                    float e = __builtin_amdgcn_exp2f(qs[r][c] * ka[c] + bb[r][u]);
                    den[r][c] += e;
                    acc[r][c] += e * va[c];
                }
            }
        }
    }
#pragma unroll
    for (int r = 0; r < 4; r++)
#pragma unroll
        for (int c = 0; c < 4; c++) {
            den[r][c] = quad_sum(den[r][c]);
            acc[r][c] = quad_sum(acc[r][c]);
        }
    if (jp == 0) {
#pragma unroll
        for (int r = 0; r < 4; r++) {
            float4 g4 = *(const float4*)&g_t[(size_t)(h * M_ROWS + mrow[r]) * D_DIM + d0];
            float o[4];
            o[0] = g4.x * acc[r][0] / den[r][0];
            o[1] = g4.y * acc[r][1] / den[r][1];
            o[2] = g4.z * acc[r][2] / den[r][2];
            o[3] = g4.w * acc[r][3] / den[r][3];
            unsigned short hi[4], lo[4];
#pragma unroll
            for (int c = 0; c < 4; c++) {
                hi[c] = bf16rn(o[c]);
                lo[c] = bf16rn(o[c] - __uint_as_float((unsigned)hi[c] << 16));
            }
            size_t base = (size_t)mrow[r] * 256 + h * 32 + d0;
            uint2 ph, pl;
            ph.x = (unsigned)hi[0] | ((unsigned)hi[1] << 16);
            ph.y = (unsigned)hi[2] | ((unsigned)hi[3] << 16);
            pl.x = (unsigned)lo[0] | ((unsigned)lo[1] << 16);
            pl.y = (unsigned)lo[2] | ((unsigned)lo[3] << 16);
            *(uint2*)&ao_hi[base] = ph;
            *(uint2*)&ao_lo[base] = pl;
        }
    }
}

// ------- Kernel 4: out projection via bf16x3 MFMA + bias -------------------
__global__ __launch_bounds__(256) void out_mfma_kernel(
    const unsigned short* __restrict__ ahi, const unsigned short* __restrict__ alo,
    const unsigned short* __restrict__ whi, const unsigned short* __restrict__ wlo,
    const float* __restrict__ bias, float* __restrict__ out)
{
    __shared__ unsigned short As[64 * 72];
    __shared__ unsigned short Bs[128 * 72];
    __shared__ float Cs[64 * 132];
    int t = threadIdx.x;
    int n0 = blockIdx.x * 128, m0 = blockIdx.y * 64;
    int w = t >> 6, L = t & 63;
    int wm = (w & 1) * 32, wn = (w >> 1) * 64;
    int l15 = L & 15, l4 = L >> 4;
    int alm = t >> 3, alk = (t & 7) * 8;
    floatx4 acc[2][4];
#pragma unroll
    for (int a = 0; a < 2; a++)
#pragma unroll
        for (int b = 0; b < 4; b++) acc[a][b] = (floatx4){0, 0, 0, 0};

    short8 pa0 = *(const short8*)&ahi[(m0 + alm) * 256 + alk];
    short8 pa1 = *(const short8*)&ahi[(m0 + alm + 32) * 256 + alk];
    short8 pb[4];
#pragma unroll
    for (int j = 0; j < 4; j++) {
        int id = t + 256 * j;
        int bn = id >> 3, bc = (id & 7) * 8;
        pb[j] = *(const short8*)&whi[(n0 + bn) * 256 + bc];
    }

    for (int r = 0; r < 12; r++) {
        __syncthreads();
        *(short8*)&As[alm * 72 + alk] = pa0;
        *(short8*)&As[(alm + 32) * 72 + alk] = pa1;
#pragma unroll
        for (int j = 0; j < 4; j++) {
            int id = t + 256 * j;
            int bn = id >> 3, bc = (id & 7) * 8;
            *(short8*)&Bs[bn * 72 + bc] = pb[j];
        }
        __syncthreads();
        if (r < 11) {
            int rn = r + 1;
            int seg = rn >> 2, kb = (rn & 3) * 64;
            const unsigned short* An = (seg == 1) ? alo : ahi;
            const unsigned short* Bn = (seg == 2) ? wlo : whi;
            pa0 = *(const short8*)&An[(m0 + alm) * 256 + kb + alk];
            pa1 = *(const short8*)&An[(m0 + alm + 32) * 256 + kb + alk];
#pragma unroll
            for (int j = 0; j < 4; j++) {
                int id = t + 256 * j;
                int bn = id >> 3, bc = (id & 7) * 8;
                pb[j] = *(const short8*)&Bn[(n0 + bn) * 256 + kb + bc];
            }
        }
#pragma unroll
        for (int ks = 0; ks < 2; ks++) {
            int ko = ks * 32 + l4 * 8;
            short8 af[2], bf[4];
#pragma unroll
            for (int a = 0; a < 2; a++)
                af[a] = *(short8*)&As[(wm + a * 16 + l15) * 72 + ko];
#pragma unroll
            for (int b = 0; b < 4; b++)
                bf[b] = *(short8*)&Bs[(wn + b * 16 + l15) * 72 + ko];
#pragma unroll
            for (int a = 0; a < 2; a++)
#pragma unroll
                for (int b = 0; b < 4; b++)
                    acc[a][b] = __builtin_amdgcn_mfma_f32_16x16x32_bf16(
                        af[a], bf[b], acc[a][b], 0, 0, 0);
        }
    }
#pragma unroll
    for (int a = 0; a < 2; a++)
#pragma unroll
        for (int b = 0; b < 4; b++) {
            int nl = wn + b * 16 + l15;
#pragma unroll
            for (int rg = 0; rg < 4; rg++) {
                int ml = wm + a * 16 + l4 * 4 + rg;
                Cs[ml * 132 + nl] = acc[a][b][rg];
            }
        }
    __syncthreads();
#pragma unroll
    for (int j = 0; j < 8; j++) {
        int id = t + 256 * j;
        int m = id >> 5, nc = (id & 31) * 4;
        float4 v = *(float4*)&Cs[m * 132 + nc];
        float4 bb = *(const float4*)&bias[n0 + nc];
        float4 o;
        o.x = v.x + bb.x; o.y = v.y + bb.y;
        o.z = v.z + bb.z; o.w = v.w + bb.w;
        *(float4*)&out[(size_t)(m0 + m) * 256 + n0 + nc] = o;
    }
}

extern "C" void kernel_launch(void* const* d_in, const int* in_sizes, int n_in,
                              void* d_out, int out_size, void* d_ws, size_t ws_size,
                              hipStream_t stream)
{
    const float* msa_rep   = (const float*)d_in[0];
    const float* pair_rep  = (const float*)d_in[1];
    const float* ln_w      = (const float*)d_in[2];
    const float* ln_b      = (const float*)d_in[3];
    const float* w_qkv     = (const float*)d_in[4];
    const float* ln_pair_w = (const float*)d_in[5];
    const float* ln_pair_b = (const float*)d_in[6];
    const float* w_b       = (const float*)d_in[7];
    const float* w_g       = (const float*)d_in[8];
    const float* w_out     = (const float*)d_in[9];
    const float* b_out     = (const float*)d_in[10];
    float* out = (float*)d_out;

    float* ws = (float*)d_ws;
    const size_t CH = 524288;     // 2048*256 floats
    float* q_t = ws + 0 * CH;
    float* k_t = ws + 1 * CH;
    float* v_t = ws + 2 * CH;
    float* g_t = ws + 3 * CH;
    float* b2  = ws + 4 * CH;
    unsigned short* ao_hi   = (unsigned short*)(ws + 5 * CH);
    unsigned short* ao_lo   = ao_hi + (size_t)M_ROWS * 256;
    unsigned short* xhi     = (unsigned short*)(ws + 6 * CH);
    unsigned short* xlo     = xhi + (size_t)M_ROWS * 256;
    unsigned short* whiT    = (unsigned short*)(ws + 7 * CH);
    unsigned short* wloT    = whiT + (size_t)XW_N * 256;
    unsigned short* wouthiT = (unsigned short*)(ws + 8 * CH);
    unsigned short* woutloT = wouthiT + 65536;

    prep_kernel<<<3232, 256, 0, stream>>>(
        pair_rep, ln_pair_w, ln_pair_b, w_b, b2,
        w_qkv, w_g, whiT, wloT,
        w_out, wouthiT, woutloT,
        msa_rep, ln_w, ln_b, xhi, xlo);

    xw_mfma_kernel<<<dim3(8, 32), 256, 0, stream>>>(
        xhi, xlo, whiT, wloT, q_t, k_t, v_t, g_t);

    attn_kernel<<<512, 256, 0, stream>>>(q_t, k_t, v_t, g_t, b2, ao_hi, ao_lo);

    out_mfma_kernel<<<dim3(2, 32), 256, 0, stream>>>(
        ao_hi, ao_lo, wouthiT, woutloT, b_out, out);
}